// Round 1
// baseline (2083.921 us; speedup 1.0000x reference)
//
#include <hip/hip_runtime.h>

#define DD 128
#define NHEAD 8
#define DH 16
#define EPS 1e-5f

// ---------------- degree computation ----------------
__global__ void k_degrees(const int* __restrict__ src, const int* __restrict__ dst,
                          float* __restrict__ outdeg, float* __restrict__ indeg, int E) {
    int e = blockIdx.x * blockDim.x + threadIdx.x;
    if (e < E) {
        atomicAdd(&outdeg[src[e]], 1.0f);
        atomicAdd(&indeg[dst[e]], 1.0f);
    }
}

// ---------------- feature scatter-add: out[dst] += x[src] ----------------
__global__ void k_scatter_feat(const float* __restrict__ x, const int* __restrict__ src,
                               const int* __restrict__ dst, float* __restrict__ out, int E) {
    int idx = blockIdx.x * blockDim.x + threadIdx.x;   // over E*128 = 76.8M (< 2^31)
    if (idx >= E * DD) return;
    int e = idx >> 7, f = idx & (DD - 1);
    atomicAdd(&out[dst[e] * DD + f], x[src[e] * DD + f]);
}

// ---------------- Q scatter: Q[dst] += P[src]*norm_s(src); ssum[dst] += norm_s ----------------
__global__ void k_scatter_q(const float* __restrict__ P, const int* __restrict__ src,
                            const int* __restrict__ dst, const float* __restrict__ outdeg,
                            float* __restrict__ Q, float* __restrict__ ssum, int E) {
    int idx = blockIdx.x * blockDim.x + threadIdx.x;
    if (idx >= E * DD) return;
    int e = idx >> 7, f = idx & (DD - 1);
    int s = src[e], d = dst[e];
    float od = outdeg[s];
    float ns = od > 0.f ? rsqrtf(od) : 0.f;
    atomicAdd(&Q[d * DD + f], P[s * DD + f] * ns);
    if (f == 0) atomicAdd(&ssum[d], ns);
}

// ---------------- acc = (acc + base) / (indeg + 1) ----------------
__global__ void k_combine_div(float* __restrict__ acc, const float* __restrict__ base,
                              const float* __restrict__ indeg, int n) {
    int idx = blockIdx.x * blockDim.x + threadIdx.x;
    if (idx < n) {
        int v = idx >> 7;
        acc[idx] = (acc[idx] + base[idx]) / (indeg[v] + 1.0f);
    }
}

// ---------------- per-head small GEMM: C[i](128x16) = A[i](128x128) @ B[i](128x16) ----------------
__global__ void k_wcomb(const float* __restrict__ A, const float* __restrict__ B,
                        float* __restrict__ C) {
    int i = blockIdx.x;
    const float* Ai = A + (size_t)i * DD * DD;
    const float* Bi = B + (size_t)i * DD * DH;
    float* Ci = C + (size_t)i * DD * DH;
    for (int o = threadIdx.x; o < DD * DH; o += blockDim.x) {
        int r = o >> 4, c = o & 15;
        float acc = 0.f;
        #pragma unroll 8
        for (int k = 0; k < DD; ++k) acc += Ai[r * DD + k] * Bi[k * DH + c];
        Ci[o] = acc;
    }
}

// ---------------- cvec[i][c] = b1[i]@T[i] + b2[i]@W3[i] ----------------
__global__ void k_cvec(const float* __restrict__ b1, const float* __restrict__ b2,
                       const float* __restrict__ T, const float* __restrict__ W3,
                       float* __restrict__ cvec) {
    int idx = blockIdx.x * blockDim.x + threadIdx.x;
    if (idx >= NHEAD * DH) return;
    int i = idx >> 4, c = idx & 15;
    float acc = 0.f;
    for (int k = 0; k < DD; ++k)
        acc += b1[i * DD + k] * T[(size_t)i * DD * DH + k * DH + c]
             + b2[i * DD + k] * W3[(size_t)i * DD * DH + k * DH + c];
    cvec[idx] = acc;
}

// ---------------- x = h + LN( per-head (Q_g @ M + ssum*c)*nd + b3 ) ----------------
__global__ void k_xcat_ln(const float* __restrict__ Qgt, const float* __restrict__ Qat,
                          const float* __restrict__ ssum_gt, const float* __restrict__ ssum_at,
                          const float* __restrict__ indeg_gt, const float* __restrict__ indeg_at,
                          const float* __restrict__ M, const float* __restrict__ cvec,
                          const float* __restrict__ b3, const float* __restrict__ h,
                          const float* __restrict__ ln_g, const float* __restrict__ ln_b,
                          float* __restrict__ xout) {
    const int R = 4;
    __shared__ float qs[2][R][DD];
    __shared__ float red[4];
    int j = threadIdx.x;              // output column 0..127
    int head = j >> 4, c = j & 15;
    int g = (head >> 1) & 1;          // heads 0,1,4,5 -> gt(0); 2,3,6,7 -> attr(1)
    int row0 = blockIdx.x * R;
    for (int r = 0; r < R; ++r) {
        qs[0][r][j] = Qgt[(row0 + r) * DD + j];
        qs[1][r][j] = Qat[(row0 + r) * DD + j];
    }
    __syncthreads();
    float gln = ln_g[j], bln = ln_b[j];
    float cv = cvec[head * DH + c], b3v = b3[head * DH + c];
    const float* Mh = M + (size_t)head * DD * DH + c;
    for (int r = 0; r < R; ++r) {
        int row = row0 + r;
        const float* q = qs[g][r];
        float acc = 0.f;
        #pragma unroll 8
        for (int k = 0; k < DD; ++k) acc += q[k] * Mh[k * DH];
        float ss = g ? ssum_at[row] : ssum_gt[row];
        float id = g ? indeg_at[row] : indeg_gt[row];
        float nd = id > 0.f ? rsqrtf(id) : 0.f;
        float val = (acc + ss * cv) * nd + b3v;
        // LayerNorm across 128 threads (2 waves)
        float s = val, s2 = val * val;
        for (int o = 32; o > 0; o >>= 1) { s += __shfl_down(s, o); s2 += __shfl_down(s2, o); }
        if ((j & 63) == 0) { red[(j >> 6) * 2] = s; red[(j >> 6) * 2 + 1] = s2; }
        __syncthreads();
        float su = red[0] + red[2], sq = red[1] + red[3];
        float mu = su * (1.f / DD);
        float var = sq * (1.f / DD) - mu * mu;
        xout[row * DD + j] = h[row * DD + j] + (val - mu) * rsqrtf(var + EPS) * gln + bln;
        __syncthreads();
    }
}

// ---------------- ffn1 = relu(x @ W1 + b1) ----------------
__global__ void k_ffn1(const float* __restrict__ x, const float* __restrict__ W1,
                       const float* __restrict__ b1, float* __restrict__ out) {
    const int R = 8;
    __shared__ float xs[R][DD];
    int j = threadIdx.x;
    int row0 = blockIdx.x * R;
    for (int r = 0; r < R; ++r) xs[r][j] = x[(row0 + r) * DD + j];
    __syncthreads();
    float acc[R];
    #pragma unroll
    for (int r = 0; r < R; ++r) acc[r] = 0.f;
    for (int k = 0; k < DD; ++k) {
        float w = W1[k * DD + j];
        #pragma unroll
        for (int r = 0; r < R; ++r) acc[r] += xs[r][k] * w;
    }
    float b = b1[j];
    for (int r = 0; r < R; ++r) {
        float v = acc[r] + b;
        out[(row0 + r) * DD + j] = v > 0.f ? v : 0.f;
    }
}

// ---------------- out = x + LN(ffn1 @ W2 + b2) ----------------
__global__ void k_ffn2_ln_add(const float* __restrict__ f1, const float* __restrict__ W2,
                              const float* __restrict__ b2, const float* __restrict__ x,
                              const float* __restrict__ ln_g, const float* __restrict__ ln_b,
                              float* __restrict__ out) {
    const int R = 8;
    __shared__ float fs[R][DD];
    __shared__ float red[4];
    int j = threadIdx.x;
    int row0 = blockIdx.x * R;
    for (int r = 0; r < R; ++r) fs[r][j] = f1[(row0 + r) * DD + j];
    __syncthreads();
    float acc[R];
    #pragma unroll
    for (int r = 0; r < R; ++r) acc[r] = 0.f;
    for (int k = 0; k < DD; ++k) {
        float w = W2[k * DD + j];
        #pragma unroll
        for (int r = 0; r < R; ++r) acc[r] += fs[r][k] * w;
    }
    float b = b2[j], gln = ln_g[j], bln = ln_b[j];
    for (int r = 0; r < R; ++r) {
        float val = acc[r] + b;
        float s = val, s2 = val * val;
        for (int o = 32; o > 0; o >>= 1) { s += __shfl_down(s, o); s2 += __shfl_down(s2, o); }
        if ((j & 63) == 0) { red[(j >> 6) * 2] = s; red[(j >> 6) * 2 + 1] = s2; }
        __syncthreads();
        float su = red[0] + red[2], sq = red[1] + red[3];
        float mu = su * (1.f / DD);
        float var = sq * (1.f / DD) - mu * mu;
        int row = row0 + r;
        out[row * DD + j] = x[row * DD + j] + (val - mu) * rsqrtf(var + EPS) * gln + bln;
        __syncthreads();
    }
}

extern "C" void kernel_launch(void* const* d_in, const int* in_sizes, int n_in,
                              void* d_out, int out_size, void* d_ws, size_t ws_size,
                              hipStream_t stream) {
    const float* h      = (const float*)d_in[0];
    const int*   gt_src = (const int*)d_in[1];
    const int*   gt_dst = (const int*)d_in[2];
    const int*   at_src = (const int*)d_in[3];
    const int*   at_dst = (const int*)d_in[4];
    const float* W1     = (const float*)d_in[5];
    const float* b1     = (const float*)d_in[6];
    const float* W2     = (const float*)d_in[7];
    const float* b2     = (const float*)d_in[8];
    const float* W3     = (const float*)d_in[9];
    const float* b3     = (const float*)d_in[10];
    const float* fW1    = (const float*)d_in[11];
    const float* fb1    = (const float*)d_in[12];
    const float* fW2    = (const float*)d_in[13];
    const float* fb2    = (const float*)d_in[14];
    const float* ln_g   = (const float*)d_in[15];
    const float* ln_b   = (const float*)d_in[16];

    const int E = in_sizes[1];
    const int N = in_sizes[0] / DD;
    const size_t NB = (size_t)N * DD;

    // workspace layout (~78 MB of floats)
    float* w = (float*)d_ws;
    float* bufA = w;                 // N*D
    float* bufB = bufA + NB;         // N*D
    float* Qgt  = bufB + NB;         // N*D
    float* sm   = Qgt + NB;
    float* indeg_gt  = sm;  sm += N;
    float* outdeg_gt = sm;  sm += N;
    float* indeg_at  = sm;  sm += N;
    float* outdeg_at = sm;  sm += N;
    float* ssum_gt   = sm;  sm += N;
    float* ssum_at   = sm;  sm += N;
    float* Tm   = sm;  sm += (size_t)NHEAD * DD * DH;
    float* Mm   = sm;  sm += (size_t)NHEAD * DD * DH;
    float* cvec = sm;  sm += NHEAD * DH;
    float* Qat  = (float*)d_out;     // reuse d_out as Q_attr; overwritten by final kernel

    // weight pre-combination: T = W2@W3, M = W1@T, cvec = b1@T + b2@W3
    k_wcomb<<<NHEAD, 256, 0, stream>>>(W2, W3, Tm);
    k_wcomb<<<NHEAD, 256, 0, stream>>>(W1, Tm, Mm);
    k_cvec<<<1, 128, 0, stream>>>(b1, b2, Tm, W3, cvec);

    const int TB = 256;
    const int egrid = (E + TB - 1) / TB;
    const int fgrid = (E * DD + TB - 1) / TB;
    const int ngrid = ((int)NB + TB - 1) / TB;

    for (int g = 0; g < 2; ++g) {
        const int* src = g ? at_src : gt_src;
        const int* dst = g ? at_dst : gt_dst;
        float* indeg   = g ? indeg_at : indeg_gt;
        float* outdeg  = g ? outdeg_at : outdeg_gt;
        float* ssum    = g ? ssum_at : ssum_gt;
        float* Q       = g ? Qat : Qgt;

        hipMemsetAsync(indeg, 0, N * sizeof(float), stream);
        hipMemsetAsync(outdeg, 0, N * sizeof(float), stream);
        k_degrees<<<egrid, TB, 0, stream>>>(src, dst, outdeg, indeg, E);

        // A1 = segsum(h[src]); hn1 = (A1 + h)/(indeg+1)   [in bufA]
        hipMemsetAsync(bufA, 0, NB * sizeof(float), stream);
        k_scatter_feat<<<fgrid, TB, 0, stream>>>(h, src, dst, bufA, E);
        k_combine_div<<<ngrid, TB, 0, stream>>>(bufA, h, indeg, (int)NB);

        // A2 = segsum(hn1[src]); P = (A2 + hn1)/(indeg+1)  [in bufB]
        hipMemsetAsync(bufB, 0, NB * sizeof(float), stream);
        k_scatter_feat<<<fgrid, TB, 0, stream>>>(bufA, src, dst, bufB, E);
        k_combine_div<<<ngrid, TB, 0, stream>>>(bufB, bufA, indeg, (int)NB);

        // Q = segsum((P*norm_s)[src]); ssum = segsum(norm_s[src])
        hipMemsetAsync(Q, 0, NB * sizeof(float), stream);
        hipMemsetAsync(ssum, 0, N * sizeof(float), stream);
        k_scatter_q<<<fgrid, TB, 0, stream>>>(bufB, src, dst, outdeg, Q, ssum, E);
    }

    // x = h + LN(x_cat)  -> bufA
    k_xcat_ln<<<N / 4, DD, 0, stream>>>(Qgt, Qat, ssum_gt, ssum_at, indeg_gt, indeg_at,
                                        Mm, cvec, b3, h, ln_g, ln_b, bufA);
    // ffn1 = relu(x@fW1+fb1) -> bufB
    k_ffn1<<<N / 8, DD, 0, stream>>>(bufA, fW1, fb1, bufB);
    // out = x + LN(ffn1@fW2+fb2)
    k_ffn2_ln_add<<<N / 8, DD, 0, stream>>>(bufB, fW2, fb2, bufA, ln_g, ln_b, (float*)d_out);
}

// Round 2
// 990.395 us; speedup vs baseline: 2.1041x; 2.1041x over previous
//
#include <hip/hip_runtime.h>

#define DD 128
#define C2 64          // DD/2 float2 per row
#define NHEAD 8
#define DH 16
#define EPS 1e-5f

// ---------------- CSR build: histograms ----------------
__global__ void k_hist2(const int* __restrict__ src, const int* __restrict__ dst,
                        int* __restrict__ ocnt, int* __restrict__ cnt, int E) {
    int e = blockIdx.x * blockDim.x + threadIdx.x;
    if (e < E) {
        atomicAdd(&ocnt[src[e]], 1);
        atomicAdd(&cnt[dst[e]], 1);
    }
}

// ---------------- exclusive scan of cnt[0..n) -> rowptr[0..n] (single block, 1024 thr) ----------------
__global__ void k_scan(const int* __restrict__ cnt, int* __restrict__ rowptr, int n) {
    __shared__ int carry;
    __shared__ int wsum[16];
    if (threadIdx.x == 0) carry = 0;
    __syncthreads();
    int lane = threadIdx.x & 63, w = threadIdx.x >> 6;
    for (int base = 0; base < n; base += 1024) {
        int i = base + threadIdx.x;
        int v = (i < n) ? cnt[i] : 0;
        int x = v;
        for (int o = 1; o < 64; o <<= 1) { int t = __shfl_up(x, o); if (lane >= o) x += t; }
        if (lane == 63) wsum[w] = x;
        __syncthreads();
        if (threadIdx.x < 16) {
            int t = wsum[threadIdx.x];
            for (int o = 1; o < 16; o <<= 1) { int u = __shfl_up(t, o); if (threadIdx.x >= o) t += u; }
            wsum[threadIdx.x] = t;
        }
        __syncthreads();
        int off = carry + (w > 0 ? wsum[w - 1] : 0);
        if (i < n) rowptr[i] = off + x - v;     // exclusive
        int incl = off + x;
        __syncthreads();
        if (threadIdx.x == 1023) carry = incl;
        __syncthreads();
    }
    if (threadIdx.x == 0) rowptr[n] = carry;
}

// ---------------- CSR fill ----------------
__global__ void k_fill(const int* __restrict__ src, const int* __restrict__ dst,
                       const int* __restrict__ rowptr, int* __restrict__ cursor,
                       int* __restrict__ csr_src, int E) {
    int e = blockIdx.x * blockDim.x + threadIdx.x;
    if (e < E) {
        int d = dst[e];
        int p = atomicAdd(&cursor[d], 1);
        csr_src[rowptr[d] + p] = src[e];
    }
}

// ---------------- norms: norm_s = rsqrt(outdeg), indeg_f = float(indeg) ----------------
__global__ void k_norms(const int* __restrict__ ocnt, const int* __restrict__ cnt,
                        float* __restrict__ norm_s, float* __restrict__ indeg_f, int N) {
    int v = blockIdx.x * blockDim.x + threadIdx.x;
    if (v < N) {
        int od = ocnt[v];
        norm_s[v] = od > 0 ? rsqrtf((float)od) : 0.f;
        indeg_f[v] = (float)cnt[v];
    }
}

// ---------------- pull SAGE: out[d] = (sum_{s in in(d)} x[s] + x[d]) / (indeg+1) ----------------
__global__ void k_pull_sage(const float2* __restrict__ x, const int* __restrict__ rowptr,
                            const int* __restrict__ csr_src, float2* __restrict__ out, int N) {
    int node = blockIdx.x * 4 + (threadIdx.x >> 6);
    int lane = threadIdx.x & 63;
    if (node >= N) return;
    int beg = rowptr[node], end = rowptr[node + 1];
    float2 self = x[(size_t)node * C2 + lane];
    float ax = self.x, ay = self.y;
    for (int e = beg; e < end; ++e) {
        int s = csr_src[e];
        float2 v = x[(size_t)s * C2 + lane];
        ax += v.x; ay += v.y;
    }
    float inv = 1.f / (float)(end - beg + 1);
    out[(size_t)node * C2 + lane] = make_float2(ax * inv, ay * inv);
}

// ---------------- pull Q: Q[d] = sum P[s]*norm_s[s];  ssum[d] = sum norm_s[s] ----------------
__global__ void k_pull_q(const float2* __restrict__ P, const int* __restrict__ rowptr,
                         const int* __restrict__ csr_src, const float* __restrict__ norm_s,
                         float2* __restrict__ Q, float* __restrict__ ssum, int N) {
    int node = blockIdx.x * 4 + (threadIdx.x >> 6);
    int lane = threadIdx.x & 63;
    if (node >= N) return;
    int beg = rowptr[node], end = rowptr[node + 1];
    float ax = 0.f, ay = 0.f, ss = 0.f;
    for (int e = beg; e < end; ++e) {
        int s = csr_src[e];
        float ns = norm_s[s];
        float2 v = P[(size_t)s * C2 + lane];
        ax += v.x * ns; ay += v.y * ns; ss += ns;
    }
    Q[(size_t)node * C2 + lane] = make_float2(ax, ay);
    if (lane == 0) ssum[node] = ss;
}

// ---------------- per-head small GEMM: C[i](128x16) = A[i](128x128) @ B[i](128x16) ----------------
__global__ void k_wcomb(const float* __restrict__ A, const float* __restrict__ B,
                        float* __restrict__ C) {
    int i = blockIdx.x;
    const float* Ai = A + (size_t)i * DD * DD;
    const float* Bi = B + (size_t)i * DD * DH;
    float* Ci = C + (size_t)i * DD * DH;
    for (int o = threadIdx.x; o < DD * DH; o += blockDim.x) {
        int r = o >> 4, c = o & 15;
        float acc = 0.f;
        #pragma unroll 8
        for (int k = 0; k < DD; ++k) acc += Ai[r * DD + k] * Bi[k * DH + c];
        Ci[o] = acc;
    }
}

// ---------------- cvec[i][c] = b1[i]@T[i] + b2[i]@W3[i] ----------------
__global__ void k_cvec(const float* __restrict__ b1, const float* __restrict__ b2,
                       const float* __restrict__ T, const float* __restrict__ W3,
                       float* __restrict__ cvec) {
    int idx = blockIdx.x * blockDim.x + threadIdx.x;
    if (idx >= NHEAD * DH) return;
    int i = idx >> 4, c = idx & 15;
    float acc = 0.f;
    for (int k = 0; k < DD; ++k)
        acc += b1[i * DD + k] * T[(size_t)i * DD * DH + k * DH + c]
             + b2[i * DD + k] * W3[(size_t)i * DD * DH + k * DH + c];
    cvec[idx] = acc;
}

// ---------------- x = h + LN( per-head (Q_g @ M + ssum*c)*nd + b3 ) ----------------
__global__ void k_xcat_ln(const float* __restrict__ Qgt, const float* __restrict__ Qat,
                          const float* __restrict__ ssum_gt, const float* __restrict__ ssum_at,
                          const float* __restrict__ indeg_gt, const float* __restrict__ indeg_at,
                          const float* __restrict__ M, const float* __restrict__ cvec,
                          const float* __restrict__ b3, const float* __restrict__ h,
                          const float* __restrict__ ln_g, const float* __restrict__ ln_b,
                          float* __restrict__ xout) {
    const int R = 4;
    __shared__ float qs[2][R][DD];
    __shared__ float red[4];
    int j = threadIdx.x;              // output column 0..127
    int head = j >> 4, c = j & 15;
    int g = (head >> 1) & 1;          // heads 0,1,4,5 -> gt(0); 2,3,6,7 -> attr(1)
    int row0 = blockIdx.x * R;
    for (int r = 0; r < R; ++r) {
        qs[0][r][j] = Qgt[(row0 + r) * DD + j];
        qs[1][r][j] = Qat[(row0 + r) * DD + j];
    }
    __syncthreads();
    float gln = ln_g[j], bln = ln_b[j];
    float cv = cvec[head * DH + c], b3v = b3[head * DH + c];
    const float* Mh = M + (size_t)head * DD * DH + c;
    for (int r = 0; r < R; ++r) {
        int row = row0 + r;
        const float* q = qs[g][r];
        float acc = 0.f;
        #pragma unroll 8
        for (int k = 0; k < DD; ++k) acc += q[k] * Mh[k * DH];
        float ss = g ? ssum_at[row] : ssum_gt[row];
        float id = g ? indeg_at[row] : indeg_gt[row];
        float nd = id > 0.f ? rsqrtf(id) : 0.f;
        float val = (acc + ss * cv) * nd + b3v;
        float s = val, s2 = val * val;
        for (int o = 32; o > 0; o >>= 1) { s += __shfl_down(s, o); s2 += __shfl_down(s2, o); }
        if ((j & 63) == 0) { red[(j >> 6) * 2] = s; red[(j >> 6) * 2 + 1] = s2; }
        __syncthreads();
        float su = red[0] + red[2], sq = red[1] + red[3];
        float mu = su * (1.f / DD);
        float var = sq * (1.f / DD) - mu * mu;
        xout[row * DD + j] = h[row * DD + j] + (val - mu) * rsqrtf(var + EPS) * gln + bln;
        __syncthreads();
    }
}

// ---------------- ffn1 = relu(x @ W1 + b1) ----------------
__global__ void k_ffn1(const float* __restrict__ x, const float* __restrict__ W1,
                       const float* __restrict__ b1, float* __restrict__ out) {
    const int R = 8;
    __shared__ float xs[R][DD];
    int j = threadIdx.x;
    int row0 = blockIdx.x * R;
    for (int r = 0; r < R; ++r) xs[r][j] = x[(row0 + r) * DD + j];
    __syncthreads();
    float acc[R];
    #pragma unroll
    for (int r = 0; r < R; ++r) acc[r] = 0.f;
    for (int k = 0; k < DD; ++k) {
        float w = W1[k * DD + j];
        #pragma unroll
        for (int r = 0; r < R; ++r) acc[r] += xs[r][k] * w;
    }
    float b = b1[j];
    for (int r = 0; r < R; ++r) {
        float v = acc[r] + b;
        out[(row0 + r) * DD + j] = v > 0.f ? v : 0.f;
    }
}

// ---------------- out = x + LN(ffn1 @ W2 + b2) ----------------
__global__ void k_ffn2_ln_add(const float* __restrict__ f1, const float* __restrict__ W2,
                              const float* __restrict__ b2, const float* __restrict__ x,
                              const float* __restrict__ ln_g, const float* __restrict__ ln_b,
                              float* __restrict__ out) {
    const int R = 8;
    __shared__ float fs[R][DD];
    __shared__ float red[4];
    int j = threadIdx.x;
    int row0 = blockIdx.x * R;
    for (int r = 0; r < R; ++r) fs[r][j] = f1[(row0 + r) * DD + j];
    __syncthreads();
    float acc[R];
    #pragma unroll
    for (int r = 0; r < R; ++r) acc[r] = 0.f;
    for (int k = 0; k < DD; ++k) {
        float w = W2[k * DD + j];
        #pragma unroll
        for (int r = 0; r < R; ++r) acc[r] += fs[r][k] * w;
    }
    float b = b2[j], gln = ln_g[j], bln = ln_b[j];
    for (int r = 0; r < R; ++r) {
        float val = acc[r] + b;
        float s = val, s2 = val * val;
        for (int o = 32; o > 0; o >>= 1) { s += __shfl_down(s, o); s2 += __shfl_down(s2, o); }
        if ((j & 63) == 0) { red[(j >> 6) * 2] = s; red[(j >> 6) * 2 + 1] = s2; }
        __syncthreads();
        float su = red[0] + red[2], sq = red[1] + red[3];
        float mu = su * (1.f / DD);
        float var = sq * (1.f / DD) - mu * mu;
        int row = row0 + r;
        out[row * DD + j] = x[row * DD + j] + (val - mu) * rsqrtf(var + EPS) * gln + bln;
        __syncthreads();
    }
}

extern "C" void kernel_launch(void* const* d_in, const int* in_sizes, int n_in,
                              void* d_out, int out_size, void* d_ws, size_t ws_size,
                              hipStream_t stream) {
    const float* h      = (const float*)d_in[0];
    const int*   gt_src = (const int*)d_in[1];
    const int*   gt_dst = (const int*)d_in[2];
    const int*   at_src = (const int*)d_in[3];
    const int*   at_dst = (const int*)d_in[4];
    const float* W1     = (const float*)d_in[5];
    const float* b1     = (const float*)d_in[6];
    const float* W2     = (const float*)d_in[7];
    const float* b2     = (const float*)d_in[8];
    const float* W3     = (const float*)d_in[9];
    const float* b3     = (const float*)d_in[10];
    const float* fW1    = (const float*)d_in[11];
    const float* fb1    = (const float*)d_in[12];
    const float* fW2    = (const float*)d_in[13];
    const float* fb2    = (const float*)d_in[14];
    const float* ln_g   = (const float*)d_in[15];
    const float* ln_b   = (const float*)d_in[16];

    const int E = in_sizes[1];
    const int N = in_sizes[0] / DD;
    const size_t NB = (size_t)N * DD;

    // ---- workspace layout ----
    float* w = (float*)d_ws;
    float* bufA = w;                 // N*D
    float* bufB = bufA + NB;         // N*D
    float* Qgt  = bufB + NB;         // N*D
    float* sm   = Qgt + NB;
    float* indeg_gt = sm;  sm += N;
    float* indeg_at = sm;  sm += N;
    float* ssum_gt  = sm;  sm += N;
    float* ssum_at  = sm;  sm += N;
    float* norms    = sm;  sm += N;
    float* Tm   = sm;  sm += (size_t)NHEAD * DD * DH;
    float* Mm   = sm;  sm += (size_t)NHEAD * DD * DH;
    float* cvec = sm;  sm += NHEAD * DH;
    int* ip = (int*)sm;
    int* rowptr  = ip;  ip += N + 1;
    int* cnt     = ip;  ip += N;
    int* ocnt    = ip;  ip += N;
    int* cursor  = ip;  ip += N;
    int* csr_src = ip;  ip += E;
    float* Qat  = (float*)d_out;     // reuse d_out as Q_attr; overwritten by final kernel

    // weight pre-combination: T = W2@W3, M = W1@T, cvec = b1@T + b2@W3
    k_wcomb<<<NHEAD, 256, 0, stream>>>(W2, W3, Tm);
    k_wcomb<<<NHEAD, 256, 0, stream>>>(W1, Tm, Mm);
    k_cvec<<<1, 128, 0, stream>>>(b1, b2, Tm, W3, cvec);

    const int TB = 256;
    const int egrid = (E + TB - 1) / TB;
    const int vgrid = (N + TB - 1) / TB;
    const int pgrid = (N + 3) / 4;        // 4 nodes/block, 64 lanes each

    for (int g = 0; g < 2; ++g) {
        const int* src = g ? at_src : gt_src;
        const int* dst = g ? at_dst : gt_dst;
        float* indeg   = g ? indeg_at : indeg_gt;
        float* ssum    = g ? ssum_at : ssum_gt;
        float* Q       = g ? Qat : Qgt;

        // CSR build (by dst)
        hipMemsetAsync(cnt, 0, N * sizeof(int), stream);
        hipMemsetAsync(ocnt, 0, N * sizeof(int), stream);
        k_hist2<<<egrid, TB, 0, stream>>>(src, dst, ocnt, cnt, E);
        k_scan<<<1, 1024, 0, stream>>>(cnt, rowptr, N);
        hipMemsetAsync(cursor, 0, N * sizeof(int), stream);
        k_fill<<<egrid, TB, 0, stream>>>(src, dst, rowptr, cursor, csr_src, E);
        k_norms<<<vgrid, TB, 0, stream>>>(ocnt, cnt, norms, indeg, N);

        // three pull passes (combine/divide fused)
        k_pull_sage<<<pgrid, 256, 0, stream>>>((const float2*)h, rowptr, csr_src,
                                               (float2*)bufA, N);
        k_pull_sage<<<pgrid, 256, 0, stream>>>((const float2*)bufA, rowptr, csr_src,
                                               (float2*)bufB, N);
        k_pull_q<<<pgrid, 256, 0, stream>>>((const float2*)bufB, rowptr, csr_src, norms,
                                            (float2*)Q, ssum, N);
    }

    // x = h + LN(x_cat)  -> bufA
    k_xcat_ln<<<N / 4, DD, 0, stream>>>(Qgt, Qat, ssum_gt, ssum_at, indeg_gt, indeg_at,
                                        Mm, cvec, b3, h, ln_g, ln_b, bufA);
    // ffn1 = relu(x@fW1+fb1) -> bufB
    k_ffn1<<<N / 8, DD, 0, stream>>>(bufA, fW1, fb1, bufB);
    // out = x + LN(ffn1@fW2+fb2)
    k_ffn2_ln_add<<<N / 8, DD, 0, stream>>>(bufB, fW2, fb2, bufA, ln_g, ln_b, (float*)d_out);
}

// Round 3
// 743.547 us; speedup vs baseline: 2.8027x; 1.3320x over previous
//
#include <hip/hip_runtime.h>

#define DD 128
#define NHEAD 8
#define DH 16
#define EPS 1e-5f

// ================= CSR build (both graphs fused; combined index space 2N) =================
__global__ void k_hist2(const int* __restrict__ gs, const int* __restrict__ gd,
                        const int* __restrict__ as_, const int* __restrict__ ad,
                        int* __restrict__ ocnt, int* __restrict__ cnt, int E, int N) {
    int i = blockIdx.x * blockDim.x + threadIdx.x;
    if (i >= 2 * E) return;
    int g = (i >= E);
    int e = g ? i - E : i;
    int s = g ? as_[e] : gs[e];
    int d = g ? ad[e] : gd[e];
    atomicAdd(&ocnt[g * N + s], 1);
    atomicAdd(&cnt[g * N + d], 1);
}

// 3-stage scan over n=2N counts -> exclusive rowptr
__global__ void k_scan1(const int* __restrict__ cnt, int* __restrict__ outv,
                        int* __restrict__ part, int n) {
    __shared__ int wsums[4];
    int t = threadIdx.x;                        // 256
    int base = blockIdx.x * 1024 + t * 4;
    int v0 = 0, v1 = 0, v2 = 0, v3 = 0;
    if (base + 3 < n) {
        int4 q = *(const int4*)(cnt + base);
        v0 = q.x; v1 = q.y; v2 = q.z; v3 = q.w;
    } else {
        if (base < n)     v0 = cnt[base];
        if (base + 1 < n) v1 = cnt[base + 1];
        if (base + 2 < n) v2 = cnt[base + 2];
        if (base + 3 < n) v3 = cnt[base + 3];
    }
    int s0 = v0, s1 = s0 + v1, s2 = s1 + v2, s3 = s2 + v3;
    int x = s3;
    int lane = t & 63, w = t >> 6;
    for (int o = 1; o < 64; o <<= 1) { int u = __shfl_up(x, o); if (lane >= o) x += u; }
    if (lane == 63) wsums[w] = x;
    __syncthreads();
    int wo = 0;
    for (int i = 0; i < w; ++i) wo += wsums[i];
    int excl = wo + x - s3;
    if (base < n)     outv[base]     = excl;
    if (base + 1 < n) outv[base + 1] = excl + s0;
    if (base + 2 < n) outv[base + 2] = excl + s1;
    if (base + 3 < n) outv[base + 3] = excl + s2;
    if (t == 255) part[blockIdx.x] = wo + x;
}

__global__ void k_scan2(int* __restrict__ part, int nb) {
    __shared__ int ws[4];
    int t = threadIdx.x;                        // 256
    int v = (t < nb) ? part[t] : 0;
    int x = v;
    int lane = t & 63, w = t >> 6;
    for (int o = 1; o < 64; o <<= 1) { int u = __shfl_up(x, o); if (lane >= o) x += u; }
    if (lane == 63) ws[w] = x;
    __syncthreads();
    int wo = 0;
    for (int i = 0; i < w; ++i) wo += ws[i];
    if (t < nb) part[t] = wo + x - v;
}

__global__ void k_scan3(int* __restrict__ outv, const int* __restrict__ part, int n, int total) {
    int i = blockIdx.x * blockDim.x + threadIdx.x;
    if (i < n) outv[i] += part[i >> 10];
    if (i == 0) outv[n] = total;
}

__global__ void k_fill2(const int* __restrict__ gs, const int* __restrict__ gd,
                        const int* __restrict__ as_, const int* __restrict__ ad,
                        const int* __restrict__ rowptr, int* __restrict__ cursor,
                        int* __restrict__ csr, int E, int N) {
    int i = blockIdx.x * blockDim.x + threadIdx.x;
    if (i >= 2 * E) return;
    int g = (i >= E);
    int e = g ? i - E : i;
    int s = g ? as_[e] : gs[e];
    int d = (g ? ad[e] : gd[e]) + g * N;
    int p = atomicAdd(&cursor[d], 1);
    csr[rowptr[d] + p] = s;
}

__global__ void k_norms(const int* __restrict__ ocnt, const int* __restrict__ cnt,
                        float* __restrict__ norm_s, float* __restrict__ indeg_f, int n2) {
    int v = blockIdx.x * blockDim.x + threadIdx.x;
    if (v < n2) {
        int od = ocnt[v];
        norm_s[v] = od > 0 ? rsqrtf((float)od) : 0.f;
        indeg_f[v] = (float)cnt[v];
    }
}

// ================= pull aggregation: 2 nodes per wave, float4 lanes =================
__global__ __launch_bounds__(256) void k_pull_sage(
        const float4* __restrict__ x, const int* __restrict__ rowptr,
        const int* __restrict__ csr, float4* __restrict__ out, int N) {
    int node = blockIdx.x * 8 + (threadIdx.x >> 5);
    int lane = threadIdx.x & 31;
    if (node >= N) return;
    int beg = rowptr[node], end = rowptr[node + 1];
    float4 a = x[(size_t)node * 32 + lane];     // self term
    int e = beg;
    while (e < end) {
        int nb = end - e; if (nb > 32) nb = 32;
        int idx = (lane < nb) ? csr[e + lane] : 0;
        #pragma unroll 4
        for (int d = 0; d < nb; ++d) {
            int s = __shfl(idx, d, 32);
            float4 v = x[(size_t)s * 32 + lane];
            a.x += v.x; a.y += v.y; a.z += v.z; a.w += v.w;
        }
        e += nb;
    }
    float inv = 1.f / (float)(end - beg + 1);
    a.x *= inv; a.y *= inv; a.z *= inv; a.w *= inv;
    out[(size_t)node * 32 + lane] = a;
}

__global__ __launch_bounds__(256) void k_pull_q(
        const float4* __restrict__ P, const int* __restrict__ rowptr,
        const int* __restrict__ csr, const float* __restrict__ norm_s,
        float4* __restrict__ Q, float* __restrict__ ssum, int N) {
    int node = blockIdx.x * 8 + (threadIdx.x >> 5);
    int lane = threadIdx.x & 31;
    if (node >= N) return;
    int beg = rowptr[node], end = rowptr[node + 1];
    float4 a = make_float4(0.f, 0.f, 0.f, 0.f);
    float ss = 0.f;
    int e = beg;
    while (e < end) {
        int nb = end - e; if (nb > 32) nb = 32;
        int idx = (lane < nb) ? csr[e + lane] : 0;
        #pragma unroll 4
        for (int d = 0; d < nb; ++d) {
            int s = __shfl(idx, d, 32);
            float ns = norm_s[s];
            float4 v = P[(size_t)s * 32 + lane];
            a.x += v.x * ns; a.y += v.y * ns; a.z += v.z * ns; a.w += v.w * ns;
            ss += ns;
        }
        e += nb;
    }
    Q[(size_t)node * 32 + lane] = a;
    if (lane == 0) ssum[node] = ss;
}

// ================= weight pre-combination =================
__global__ void k_wcomb(const float* __restrict__ A, const float* __restrict__ B,
                        float* __restrict__ C) {          // C[i] = A[i](128x128) @ B[i](128x16)
    int i = blockIdx.x;
    const float* Ai = A + (size_t)i * DD * DD;
    const float* Bi = B + (size_t)i * DD * DH;
    float* Ci = C + (size_t)i * DD * DH;
    for (int o = threadIdx.x; o < DD * DH; o += blockDim.x) {
        int r = o >> 4, c = o & 15;
        float acc = 0.f;
        #pragma unroll 8
        for (int k = 0; k < DD; ++k) acc += Ai[r * DD + k] * Bi[k * DH + c];
        Ci[o] = acc;
    }
}

// transposed variant: Mt[k][head*16+c] = (A[i] @ B[i])[k][c]
__global__ void k_wcombT(const float* __restrict__ A, const float* __restrict__ B,
                         float* __restrict__ Mt) {
    int i = blockIdx.x;
    const float* Ai = A + (size_t)i * DD * DD;
    const float* Bi = B + (size_t)i * DD * DH;
    for (int o = threadIdx.x; o < DD * DH; o += blockDim.x) {
        int r = o >> 4, c = o & 15;
        float acc = 0.f;
        #pragma unroll 8
        for (int k = 0; k < DD; ++k) acc += Ai[r * DD + k] * Bi[k * DH + c];
        Mt[r * DD + i * DH + c] = acc;
    }
}

__global__ void k_cvec(const float* __restrict__ b1, const float* __restrict__ b2,
                       const float* __restrict__ T, const float* __restrict__ W3,
                       float* __restrict__ cvec) {
    int idx = blockIdx.x * blockDim.x + threadIdx.x;
    if (idx >= NHEAD * DH) return;
    int i = idx >> 4, c = idx & 15;
    float acc = 0.f;
    for (int k = 0; k < DD; ++k)
        acc += b1[i * DD + k] * T[(size_t)i * DD * DH + k * DH + c]
             + b2[i * DD + k] * W3[(size_t)i * DD * DH + k * DH + c];
    cvec[idx] = acc;
}

// ================= x = h + LN( (Q_g @ M + ssum*c)*nd + b3 ) =================
__global__ __launch_bounds__(128) void k_xcat_ln(
        const float* __restrict__ Qgt, const float* __restrict__ Qat,
        const float* __restrict__ ssum, const float* __restrict__ indeg,
        const float* __restrict__ Mt, const float* __restrict__ cvec,
        const float* __restrict__ b3, const float* __restrict__ h,
        const float* __restrict__ ln_g, const float* __restrict__ ln_b,
        float* __restrict__ xout, int N) {
    const int R = 16;
    __shared__ float qs[2][R][DD];
    __shared__ float red[4];
    int j = threadIdx.x;
    int head = j >> 4, c = j & 15;
    int g = (head >> 1) & 1;
    int row0 = blockIdx.x * R;
    for (int r = 0; r < R; ++r) {
        qs[0][r][j] = Qgt[(size_t)(row0 + r) * DD + j];
        qs[1][r][j] = Qat[(size_t)(row0 + r) * DD + j];
    }
    __syncthreads();
    const float* qb = &qs[g][0][0];
    float acc[R];
    #pragma unroll
    for (int r = 0; r < R; ++r) acc[r] = 0.f;
    #pragma unroll 2
    for (int k = 0; k < DD; ++k) {
        float m = Mt[k * DD + j];               // coalesced, L2-resident
        #pragma unroll
        for (int r = 0; r < R; ++r) acc[r] += qb[r * DD + k] * m;
    }
    float gln = ln_g[j], bln = ln_b[j];
    float cv = cvec[head * DH + c], b3v = b3[head * DH + c];
    for (int r = 0; r < R; ++r) {
        int row = row0 + r;
        float ss = ssum[g * N + row];
        float id = indeg[g * N + row];
        float nd = id > 0.f ? rsqrtf(id) : 0.f;
        float val = (acc[r] + ss * cv) * nd + b3v;
        float s = val, s2 = val * val;
        for (int o = 32; o > 0; o >>= 1) { s += __shfl_down(s, o); s2 += __shfl_down(s2, o); }
        if ((j & 63) == 0) { red[(j >> 6) * 2] = s; red[(j >> 6) * 2 + 1] = s2; }
        __syncthreads();
        float su = red[0] + red[2], sq = red[1] + red[3];
        float mu = su * (1.f / DD);
        float var = sq * (1.f / DD) - mu * mu;
        xout[(size_t)row * DD + j] = h[(size_t)row * DD + j] + (val - mu) * rsqrtf(var + EPS) * gln + bln;
        __syncthreads();
    }
}

// ================= ffn1 = relu(x @ W1 + b1) =================
__global__ __launch_bounds__(128) void k_ffn1(
        const float* __restrict__ x, const float* __restrict__ W1,
        const float* __restrict__ b1, float* __restrict__ out) {
    const int R = 16;
    __shared__ float xs[R][DD];
    int j = threadIdx.x;
    int row0 = blockIdx.x * R;
    for (int r = 0; r < R; ++r) xs[r][j] = x[(size_t)(row0 + r) * DD + j];
    __syncthreads();
    float acc[R];
    #pragma unroll
    for (int r = 0; r < R; ++r) acc[r] = 0.f;
    #pragma unroll 2
    for (int k = 0; k < DD; ++k) {
        float w = W1[k * DD + j];
        #pragma unroll
        for (int r = 0; r < R; ++r) acc[r] += xs[r][k] * w;
    }
    float b = b1[j];
    for (int r = 0; r < R; ++r) {
        float v = acc[r] + b;
        out[(size_t)(row0 + r) * DD + j] = v > 0.f ? v : 0.f;
    }
}

// ================= out = x + LN(ffn1 @ W2 + b2) =================
__global__ __launch_bounds__(128) void k_ffn2_ln_add(
        const float* __restrict__ f1, const float* __restrict__ W2,
        const float* __restrict__ b2, const float* __restrict__ x,
        const float* __restrict__ ln_g, const float* __restrict__ ln_b,
        float* __restrict__ out) {
    const int R = 16;
    __shared__ float fs[R][DD];
    __shared__ float red[4];
    int j = threadIdx.x;
    int row0 = blockIdx.x * R;
    for (int r = 0; r < R; ++r) fs[r][j] = f1[(size_t)(row0 + r) * DD + j];
    __syncthreads();
    float acc[R];
    #pragma unroll
    for (int r = 0; r < R; ++r) acc[r] = 0.f;
    #pragma unroll 2
    for (int k = 0; k < DD; ++k) {
        float w = W2[k * DD + j];
        #pragma unroll
        for (int r = 0; r < R; ++r) acc[r] += fs[r][k] * w;
    }
    float b = b2[j], gln = ln_g[j], bln = ln_b[j];
    for (int r = 0; r < R; ++r) {
        float val = acc[r] + b;
        float s = val, s2 = val * val;
        for (int o = 32; o > 0; o >>= 1) { s += __shfl_down(s, o); s2 += __shfl_down(s2, o); }
        if ((j & 63) == 0) { red[(j >> 6) * 2] = s; red[(j >> 6) * 2 + 1] = s2; }
        __syncthreads();
        float su = red[0] + red[2], sq = red[1] + red[3];
        float mu = su * (1.f / DD);
        float var = sq * (1.f / DD) - mu * mu;
        int row = row0 + r;
        out[(size_t)row * DD + j] = x[(size_t)row * DD + j] + (val - mu) * rsqrtf(var + EPS) * gln + bln;
        __syncthreads();
    }
}

extern "C" void kernel_launch(void* const* d_in, const int* in_sizes, int n_in,
                              void* d_out, int out_size, void* d_ws, size_t ws_size,
                              hipStream_t stream) {
    const float* h      = (const float*)d_in[0];
    const int*   gt_src = (const int*)d_in[1];
    const int*   gt_dst = (const int*)d_in[2];
    const int*   at_src = (const int*)d_in[3];
    const int*   at_dst = (const int*)d_in[4];
    const float* W1     = (const float*)d_in[5];
    const float* b1     = (const float*)d_in[6];
    const float* W2     = (const float*)d_in[7];
    const float* b2     = (const float*)d_in[8];
    const float* W3     = (const float*)d_in[9];
    const float* b3     = (const float*)d_in[10];
    const float* fW1    = (const float*)d_in[11];
    const float* fb1    = (const float*)d_in[12];
    const float* fW2    = (const float*)d_in[13];
    const float* fb2    = (const float*)d_in[14];
    const float* ln_g   = (const float*)d_in[15];
    const float* ln_b   = (const float*)d_in[16];

    const int E = in_sizes[1];
    const int N = in_sizes[0] / DD;
    const size_t NB = (size_t)N * DD;
    const int N2 = 2 * N;

    // ---- workspace layout ----
    float* w = (float*)d_ws;
    float* bufA  = w;                // NB
    float* bufB  = bufA + NB;        // NB
    float* Qgt   = bufB + NB;        // NB
    float* sm    = Qgt + NB;
    float* norms = sm;  sm += N2;    // per-graph norm_s, combined
    float* indeg = sm;  sm += N2;
    float* ssum  = sm;  sm += N2;
    float* Tm    = sm;  sm += (size_t)NHEAD * DD * DH;
    float* Mt    = sm;  sm += DD * DD;          // transposed combined M [k][j]
    float* cvec  = sm;  sm += NHEAD * DH;
    int* ip = (int*)sm;
    int* cnt    = ip;  ip += N2;     // | cnt | ocnt | cursor | contiguous -> one memset
    int* ocnt   = ip;  ip += N2;
    int* cursor = ip;  ip += N2;
    int* rowptr = ip;  ip += N2 + 1;
    int* part   = ip;  ip += 256;
    int* csr    = ip;  ip += 2 * E;
    float* Qat  = (float*)d_out;     // reuse d_out; overwritten by final kernel

    // weight pre-combination: T = W2@W3, Mt = (W1@T)^T-packed, cvec = b1@T + b2@W3
    k_wcomb <<<NHEAD, 256, 0, stream>>>(W2, W3, Tm);
    k_wcombT<<<NHEAD, 256, 0, stream>>>(W1, Tm, Mt);
    k_cvec  <<<1, 128, 0, stream>>>(b1, b2, Tm, W3, cvec);

    const int TB = 256;
    // CSR build, both graphs fused
    hipMemsetAsync(cnt, 0, (size_t)3 * N2 * sizeof(int), stream);
    k_hist2<<<(2 * E + TB - 1) / TB, TB, 0, stream>>>(gt_src, gt_dst, at_src, at_dst,
                                                      ocnt, cnt, E, N);
    int nsb = (N2 + 1023) / 1024;
    k_scan1<<<nsb, 256, 0, stream>>>(cnt, rowptr, part, N2);
    k_scan2<<<1, 256, 0, stream>>>(part, nsb);
    k_scan3<<<(N2 + TB - 1) / TB, TB, 0, stream>>>(rowptr, part, N2, 2 * E);
    k_fill2<<<(2 * E + TB - 1) / TB, TB, 0, stream>>>(gt_src, gt_dst, at_src, at_dst,
                                                      rowptr, cursor, csr, E, N);
    k_norms<<<(N2 + TB - 1) / TB, TB, 0, stream>>>(ocnt, cnt, norms, indeg, N2);

    // pull passes: 8 nodes/block (2 per wave)
    const int pgrid = (N + 7) / 8;
    for (int g = 0; g < 2; ++g) {
        const int* rp = rowptr + g * N;
        float* Q = g ? Qat : Qgt;
        k_pull_sage<<<pgrid, 256, 0, stream>>>((const float4*)h, rp, csr, (float4*)bufA, N);
        k_pull_sage<<<pgrid, 256, 0, stream>>>((const float4*)bufA, rp, csr, (float4*)bufB, N);
        k_pull_q<<<pgrid, 256, 0, stream>>>((const float4*)bufB, rp, csr, norms + g * N,
                                            (float4*)Q, ssum + g * N, N);
    }

    // x = h + LN(x_cat) -> bufA
    k_xcat_ln<<<N / 16, DD, 0, stream>>>(Qgt, Qat, ssum, indeg, Mt, cvec, b3, h,
                                         ln_g, ln_b, bufA, N);
    // ffn1 = relu(x@fW1+fb1) -> bufB
    k_ffn1<<<N / 16, DD, 0, stream>>>(bufA, fW1, fb1, bufB);
    // out = x + LN(ffn1@fW2+fb2)
    k_ffn2_ln_add<<<N / 16, DD, 0, stream>>>(bufB, fW2, fb2, bufA, ln_g, ln_b, (float*)d_out);
}

// Round 4
// 623.022 us; speedup vs baseline: 3.3449x; 1.1935x over previous
//
#include <hip/hip_runtime.h>

#define DD 128
#define NHEAD 8
#define DH 16
#define EPS 1e-5f
#define BSH 9                 // bucket width 512 nodes
#define BWIDTH 512
#define NBLK1 256             // pass-1 blocks

// ================= pass 1a: per-block bucket histograms (dst-keys then src-keys) ==========
__global__ __launch_bounds__(256) void k_p1count(
        const int* __restrict__ gs, const int* __restrict__ gd,
        const int* __restrict__ as_, const int* __restrict__ ad,
        int* __restrict__ blkcnt, int E, int N, int Btot) {
    __shared__ int cnts[512];
    for (int j = threadIdx.x; j < 2 * Btot; j += 256) cnts[j] = 0;
    __syncthreads();
    int E2 = 2 * E;
    for (int i = blockIdx.x * 256 + threadIdx.x; i < E2; i += NBLK1 * 256) {
        int g = (i >= E);
        int e = g ? i - E : i;
        int s = g ? as_[e] : gs[e];
        int d = g ? ad[e] : gd[e];
        int cd = d + g * N, cs = s + g * N;
        atomicAdd(&cnts[cd >> BSH], 1);
        atomicAdd(&cnts[Btot + (cs >> BSH)], 1);
    }
    __syncthreads();
    for (int j = threadIdx.x; j < 2 * Btot; j += 256)
        blkcnt[j * NBLK1 + blockIdx.x] = cnts[j];
}

// ================= 3-stage scan (over blkcnt, n up to 262k) =================
__global__ void k_scan1(const int* __restrict__ cnt, int* __restrict__ outv,
                        int* __restrict__ part, int n) {
    __shared__ int wsums[4];
    int t = threadIdx.x;
    int base = blockIdx.x * 1024 + t * 4;
    int v0 = 0, v1 = 0, v2 = 0, v3 = 0;
    if (base + 3 < n) {
        int4 q = *(const int4*)(cnt + base);
        v0 = q.x; v1 = q.y; v2 = q.z; v3 = q.w;
    } else {
        if (base < n)     v0 = cnt[base];
        if (base + 1 < n) v1 = cnt[base + 1];
        if (base + 2 < n) v2 = cnt[base + 2];
        if (base + 3 < n) v3 = cnt[base + 3];
    }
    int s0 = v0, s1 = s0 + v1, s2 = s1 + v2, s3 = s2 + v3;
    int x = s3;
    int lane = t & 63, w = t >> 6;
    for (int o = 1; o < 64; o <<= 1) { int u = __shfl_up(x, o); if (lane >= o) x += u; }
    if (lane == 63) wsums[w] = x;
    __syncthreads();
    int wo = 0;
    for (int i = 0; i < w; ++i) wo += wsums[i];
    int excl = wo + x - s3;
    if (base < n)     outv[base]     = excl;
    if (base + 1 < n) outv[base + 1] = excl + s0;
    if (base + 2 < n) outv[base + 2] = excl + s1;
    if (base + 3 < n) outv[base + 3] = excl + s2;
    if (t == 255) part[blockIdx.x] = wo + x;
}

__global__ void k_scan2(int* __restrict__ part, int nb) {
    __shared__ int ws[4];
    int t = threadIdx.x;
    int v = (t < nb) ? part[t] : 0;
    int x = v;
    int lane = t & 63, w = t >> 6;
    for (int o = 1; o < 64; o <<= 1) { int u = __shfl_up(x, o); if (lane >= o) x += u; }
    if (lane == 63) ws[w] = x;
    __syncthreads();
    int wo = 0;
    for (int i = 0; i < w; ++i) wo += ws[i];
    if (t < nb) part[t] = wo + x - v;
}

__global__ void k_scan3(int* __restrict__ outv, const int* __restrict__ part, int n, int total) {
    int i = blockIdx.x * blockDim.x + threadIdx.x;
    if (i < n) outv[i] += part[i >> 10];
    if (i == 0) outv[n] = total;
}

// ================= pass 1b: scatter edges into bucket regions =================
__global__ __launch_bounds__(256) void k_p1scatter(
        const int* __restrict__ gs, const int* __restrict__ gd,
        const int* __restrict__ as_, const int* __restrict__ ad,
        const int* __restrict__ scn, int2* __restrict__ pairs, int* __restrict__ svals,
        int E, int N, int Btot) {
    __shared__ int cur[512];
    for (int j = threadIdx.x; j < 2 * Btot; j += 256)
        cur[j] = scn[j * NBLK1 + blockIdx.x];
    __syncthreads();
    int E2 = 2 * E;
    for (int i = blockIdx.x * 256 + threadIdx.x; i < E2; i += NBLK1 * 256) {
        int g = (i >= E);
        int e = g ? i - E : i;
        int s = g ? as_[e] : gs[e];
        int d = g ? ad[e] : gd[e];
        int cd = d + g * N, cs = s + g * N;
        int pd = atomicAdd(&cur[cd >> BSH], 1);
        pairs[pd] = make_int2(cd, s);                  // payload = raw src id
        int ps = atomicAdd(&cur[Btot + (cs >> BSH)], 1);
        svals[ps - E2] = cs;
    }
}

// ================= pass 2: per-bucket CSR + indeg + norms =================
__global__ __launch_bounds__(256) void k_p2(
        const int2* __restrict__ pairs, const int* __restrict__ svals,
        const int* __restrict__ scn, int* __restrict__ rowptr, int* __restrict__ csr,
        float* __restrict__ indeg, float* __restrict__ norms,
        int E, int N2, int Btot) {
    __shared__ int hist[BWIDTH];
    __shared__ int offs[BWIDTH];
    __shared__ int cur[BWIDTH];
    __shared__ int ws4[4];
    int b = blockIdx.x, t = threadIdx.x;
    int node0 = b << BSH;
    int W = N2 - node0; if (W > BWIDTH) W = BWIDTH;
    int Sd = scn[b * NBLK1], Ed = scn[(b + 1) * NBLK1];
    // --- dst histogram ---
    hist[t] = 0; hist[t + 256] = 0;
    __syncthreads();
    for (int i = Sd + t; i < Ed; i += 256) {
        int2 p = pairs[i];
        atomicAdd(&hist[p.x - node0], 1);
    }
    __syncthreads();
    // --- exclusive scan of hist[0..512) ---
    int a0 = hist[2 * t], a1 = hist[2 * t + 1];
    int sum2 = a0 + a1;
    int lane = t & 63, w = t >> 6;
    int x = sum2;
    for (int o = 1; o < 64; o <<= 1) { int u = __shfl_up(x, o); if (lane >= o) x += u; }
    if (lane == 63) ws4[w] = x;
    __syncthreads();
    int wo = 0;
    for (int i = 0; i < w; ++i) wo += ws4[i];
    int excl2 = wo + x - sum2;
    offs[2 * t] = excl2; offs[2 * t + 1] = excl2 + a0;
    cur[t] = 0; cur[t + 256] = 0;
    __syncthreads();
    // --- rowptr / indeg ---
    for (int j = t; j < W; j += 256) {
        rowptr[node0 + j] = Sd + offs[j];
        indeg[node0 + j] = (float)hist[j];
    }
    if (b == 0 && t == 0) rowptr[N2] = 2 * E;
    // --- csr scatter ---
    for (int i = Sd + t; i < Ed; i += 256) {
        int2 p = pairs[i];
        int l = p.x - node0;
        int pos = atomicAdd(&cur[l], 1);
        csr[Sd + offs[l] + pos] = p.y;
    }
    // --- src histogram -> norms ---
    __syncthreads();
    hist[t] = 0; hist[t + 256] = 0;
    __syncthreads();
    int Ss = scn[(Btot + b) * NBLK1] - 2 * E;
    int Es = scn[(Btot + b + 1) * NBLK1] - 2 * E;
    for (int i = Ss + t; i < Es; i += 256)
        atomicAdd(&hist[svals[i] - node0], 1);
    __syncthreads();
    for (int j = t; j < W; j += 256) {
        int od = hist[j];
        norms[node0 + j] = od > 0 ? rsqrtf((float)od) : 0.f;
    }
}

// ================= pull aggregation: 2 nodes per wave, float4 lanes =================
__global__ __launch_bounds__(256) void k_pull_sage(
        const float4* __restrict__ x, const int* __restrict__ rowptr,
        const int* __restrict__ csr, float4* __restrict__ out, int N) {
    int node = blockIdx.x * 8 + (threadIdx.x >> 5);
    int lane = threadIdx.x & 31;
    if (node >= N) return;
    int beg = rowptr[node], end = rowptr[node + 1];
    float4 a = x[(size_t)node * 32 + lane];     // self term
    int e = beg;
    while (e < end) {
        int nb = end - e; if (nb > 32) nb = 32;
        int idx = (lane < nb) ? csr[e + lane] : 0;
        #pragma unroll 4
        for (int d = 0; d < nb; ++d) {
            int s = __shfl(idx, d, 32);
            float4 v = x[(size_t)s * 32 + lane];
            a.x += v.x; a.y += v.y; a.z += v.z; a.w += v.w;
        }
        e += nb;
    }
    float inv = 1.f / (float)(end - beg + 1);
    a.x *= inv; a.y *= inv; a.z *= inv; a.w *= inv;
    out[(size_t)node * 32 + lane] = a;
}

__global__ __launch_bounds__(256) void k_pull_q(
        const float4* __restrict__ P, const int* __restrict__ rowptr,
        const int* __restrict__ csr, const float* __restrict__ norm_s,
        float4* __restrict__ Q, float* __restrict__ ssum, int N) {
    int node = blockIdx.x * 8 + (threadIdx.x >> 5);
    int lane = threadIdx.x & 31;
    if (node >= N) return;
    int beg = rowptr[node], end = rowptr[node + 1];
    float4 a = make_float4(0.f, 0.f, 0.f, 0.f);
    float ss = 0.f;
    int e = beg;
    while (e < end) {
        int nb = end - e; if (nb > 32) nb = 32;
        int idx = (lane < nb) ? csr[e + lane] : 0;
        #pragma unroll 4
        for (int d = 0; d < nb; ++d) {
            int s = __shfl(idx, d, 32);
            float ns = norm_s[s];
            float4 v = P[(size_t)s * 32 + lane];
            a.x += v.x * ns; a.y += v.y * ns; a.z += v.z * ns; a.w += v.w * ns;
            ss += ns;
        }
        e += nb;
    }
    Q[(size_t)node * 32 + lane] = a;
    if (lane == 0) ssum[node] = ss;
}

// ================= weight pre-combination =================
__global__ void k_wcomb(const float* __restrict__ A, const float* __restrict__ B,
                        float* __restrict__ C) {          // C[i] = A[i](128x128) @ B[i](128x16)
    int i = blockIdx.x;
    const float* Ai = A + (size_t)i * DD * DD;
    const float* Bi = B + (size_t)i * DD * DH;
    float* Ci = C + (size_t)i * DD * DH;
    for (int o = threadIdx.x; o < DD * DH; o += blockDim.x) {
        int r = o >> 4, c = o & 15;
        float acc = 0.f;
        #pragma unroll 8
        for (int k = 0; k < DD; ++k) acc += Ai[r * DD + k] * Bi[k * DH + c];
        Ci[o] = acc;
    }
}

// transposed variant: Mt[k][head*16+c] = (A[i] @ B[i])[k][c]
__global__ void k_wcombT(const float* __restrict__ A, const float* __restrict__ B,
                         float* __restrict__ Mt) {
    int i = blockIdx.x;
    const float* Ai = A + (size_t)i * DD * DD;
    const float* Bi = B + (size_t)i * DD * DH;
    for (int o = threadIdx.x; o < DD * DH; o += blockDim.x) {
        int r = o >> 4, c = o & 15;
        float acc = 0.f;
        #pragma unroll 8
        for (int k = 0; k < DD; ++k) acc += Ai[r * DD + k] * Bi[k * DH + c];
        Mt[r * DD + i * DH + c] = acc;
    }
}

__global__ void k_cvec(const float* __restrict__ b1, const float* __restrict__ b2,
                       const float* __restrict__ T, const float* __restrict__ W3,
                       float* __restrict__ cvec) {
    int idx = blockIdx.x * blockDim.x + threadIdx.x;
    if (idx >= NHEAD * DH) return;
    int i = idx >> 4, c = idx & 15;
    float acc = 0.f;
    for (int k = 0; k < DD; ++k)
        acc += b1[i * DD + k] * T[(size_t)i * DD * DH + k * DH + c]
             + b2[i * DD + k] * W3[(size_t)i * DD * DH + k * DH + c];
    cvec[idx] = acc;
}

// ================= x = h + LN( (Q_g @ M + ssum*c)*nd + b3 ) =================
__global__ __launch_bounds__(128) void k_xcat_ln(
        const float* __restrict__ Qgt, const float* __restrict__ Qat,
        const float* __restrict__ ssum, const float* __restrict__ indeg,
        const float* __restrict__ Mt, const float* __restrict__ cvec,
        const float* __restrict__ b3, const float* __restrict__ h,
        const float* __restrict__ ln_g, const float* __restrict__ ln_b,
        float* __restrict__ xout, int N) {
    const int R = 16;
    __shared__ float qs[2][R][DD];
    __shared__ float red[4];
    int j = threadIdx.x;
    int head = j >> 4, c = j & 15;
    int g = (head >> 1) & 1;
    int row0 = blockIdx.x * R;
    for (int r = 0; r < R; ++r) {
        qs[0][r][j] = Qgt[(size_t)(row0 + r) * DD + j];
        qs[1][r][j] = Qat[(size_t)(row0 + r) * DD + j];
    }
    __syncthreads();
    const float* qb = &qs[g][0][0];
    float acc[R];
    #pragma unroll
    for (int r = 0; r < R; ++r) acc[r] = 0.f;
    #pragma unroll 2
    for (int k = 0; k < DD; ++k) {
        float m = Mt[k * DD + j];
        #pragma unroll
        for (int r = 0; r < R; ++r) acc[r] += qb[r * DD + k] * m;
    }
    float gln = ln_g[j], bln = ln_b[j];
    float cv = cvec[head * DH + c], b3v = b3[head * DH + c];
    for (int r = 0; r < R; ++r) {
        int row = row0 + r;
        float ss = ssum[g * N + row];
        float id = indeg[g * N + row];
        float nd = id > 0.f ? rsqrtf(id) : 0.f;
        float val = (acc[r] + ss * cv) * nd + b3v;
        float s = val, s2 = val * val;
        for (int o = 32; o > 0; o >>= 1) { s += __shfl_down(s, o); s2 += __shfl_down(s2, o); }
        if ((j & 63) == 0) { red[(j >> 6) * 2] = s; red[(j >> 6) * 2 + 1] = s2; }
        __syncthreads();
        float su = red[0] + red[2], sq = red[1] + red[3];
        float mu = su * (1.f / DD);
        float var = sq * (1.f / DD) - mu * mu;
        xout[(size_t)row * DD + j] = h[(size_t)row * DD + j] + (val - mu) * rsqrtf(var + EPS) * gln + bln;
        __syncthreads();
    }
}

// ================= ffn1 = relu(x @ W1 + b1) =================
__global__ __launch_bounds__(128) void k_ffn1(
        const float* __restrict__ x, const float* __restrict__ W1,
        const float* __restrict__ b1, float* __restrict__ out) {
    const int R = 16;
    __shared__ float xs[R][DD];
    int j = threadIdx.x;
    int row0 = blockIdx.x * R;
    for (int r = 0; r < R; ++r) xs[r][j] = x[(size_t)(row0 + r) * DD + j];
    __syncthreads();
    float acc[R];
    #pragma unroll
    for (int r = 0; r < R; ++r) acc[r] = 0.f;
    #pragma unroll 2
    for (int k = 0; k < DD; ++k) {
        float w = W1[k * DD + j];
        #pragma unroll
        for (int r = 0; r < R; ++r) acc[r] += xs[r][k] * w;
    }
    float b = b1[j];
    for (int r = 0; r < R; ++r) {
        float v = acc[r] + b;
        out[(size_t)(row0 + r) * DD + j] = v > 0.f ? v : 0.f;
    }
}

// ================= out = x + LN(ffn1 @ W2 + b2) =================
__global__ __launch_bounds__(128) void k_ffn2_ln_add(
        const float* __restrict__ f1, const float* __restrict__ W2,
        const float* __restrict__ b2, const float* __restrict__ x,
        const float* __restrict__ ln_g, const float* __restrict__ ln_b,
        float* __restrict__ out) {
    const int R = 16;
    __shared__ float fs[R][DD];
    __shared__ float red[4];
    int j = threadIdx.x;
    int row0 = blockIdx.x * R;
    for (int r = 0; r < R; ++r) fs[r][j] = f1[(size_t)(row0 + r) * DD + j];
    __syncthreads();
    float acc[R];
    #pragma unroll
    for (int r = 0; r < R; ++r) acc[r] = 0.f;
    #pragma unroll 2
    for (int k = 0; k < DD; ++k) {
        float w = W2[k * DD + j];
        #pragma unroll
        for (int r = 0; r < R; ++r) acc[r] += fs[r][k] * w;
    }
    float b = b2[j], gln = ln_g[j], bln = ln_b[j];
    for (int r = 0; r < R; ++r) {
        float val = acc[r] + b;
        float s = val, s2 = val * val;
        for (int o = 32; o > 0; o >>= 1) { s += __shfl_down(s, o); s2 += __shfl_down(s2, o); }
        if ((j & 63) == 0) { red[(j >> 6) * 2] = s; red[(j >> 6) * 2 + 1] = s2; }
        __syncthreads();
        float su = red[0] + red[2], sq = red[1] + red[3];
        float mu = su * (1.f / DD);
        float var = sq * (1.f / DD) - mu * mu;
        int row = row0 + r;
        out[(size_t)row * DD + j] = x[(size_t)row * DD + j] + (val - mu) * rsqrtf(var + EPS) * gln + bln;
        __syncthreads();
    }
}

extern "C" void kernel_launch(void* const* d_in, const int* in_sizes, int n_in,
                              void* d_out, int out_size, void* d_ws, size_t ws_size,
                              hipStream_t stream) {
    const float* h      = (const float*)d_in[0];
    const int*   gt_src = (const int*)d_in[1];
    const int*   gt_dst = (const int*)d_in[2];
    const int*   at_src = (const int*)d_in[3];
    const int*   at_dst = (const int*)d_in[4];
    const float* W1     = (const float*)d_in[5];
    const float* b1     = (const float*)d_in[6];
    const float* W2     = (const float*)d_in[7];
    const float* b2     = (const float*)d_in[8];
    const float* W3     = (const float*)d_in[9];
    const float* b3     = (const float*)d_in[10];
    const float* fW1    = (const float*)d_in[11];
    const float* fb1    = (const float*)d_in[12];
    const float* fW2    = (const float*)d_in[13];
    const float* fb2    = (const float*)d_in[14];
    const float* ln_g   = (const float*)d_in[15];
    const float* ln_b   = (const float*)d_in[16];

    const int E = in_sizes[1];
    const int N = in_sizes[0] / DD;
    const size_t NB = (size_t)N * DD;
    const int N2 = 2 * N;
    const int Btot = (N2 + BWIDTH - 1) >> BSH;
    const int n1 = 2 * Btot * NBLK1;      // blkcnt length

    // ---- workspace layout ----
    float* w = (float*)d_ws;
    float* bufA  = w;                // NB
    float* bufB  = bufA + NB;        // NB
    float* Qgt   = bufB + NB;        // NB
    float* sm    = Qgt + NB;
    float* norms = sm;  sm += N2;
    float* indeg = sm;  sm += N2;
    float* ssum  = sm;  sm += N2;
    float* Tm    = sm;  sm += (size_t)NHEAD * DD * DH;
    float* Mt    = sm;  sm += DD * DD;
    float* cvec  = sm;  sm += NHEAD * DH + 32;   // pad for alignment
    int* ip = (int*)sm;
    int* rowptr = ip;  ip += ((N2 + 1 + 3) & ~3);
    int* csr    = ip;  ip += 2 * E;
    int* blkcnt = ip;  ip += ((n1 + 1 + 3) & ~3);
    int* scn    = ip;  ip += ((n1 + 1 + 3) & ~3);
    int* part   = ip;  ip += 256;
    // CSR-build scratch aliased over bufA (free until first pull)
    int2* pairs = (int2*)bufA;                    // 2E int2 = 9.6 MB
    int*  svals = (int*)(pairs + 2 * E);          // 2E int  = 4.8 MB  (< 25.6 MB of bufA)
    float* Qat  = (float*)d_out;     // reuse d_out; overwritten by final kernel

    // weight pre-combination: T = W2@W3, Mt = (W1@T)^T-packed, cvec = b1@T + b2@W3
    k_wcomb <<<NHEAD, 256, 0, stream>>>(W2, W3, Tm);
    k_wcombT<<<NHEAD, 256, 0, stream>>>(W1, Tm, Mt);
    k_cvec  <<<1, 128, 0, stream>>>(b1, b2, Tm, W3, cvec);

    const int TB = 256;
    // ---- CSR build: bucketed counting sort, no global atomics ----
    k_p1count<<<NBLK1, 256, 0, stream>>>(gt_src, gt_dst, at_src, at_dst, blkcnt, E, N, Btot);
    int nsb = (n1 + 1023) / 1024;
    k_scan1<<<nsb, 256, 0, stream>>>(blkcnt, scn, part, n1);
    k_scan2<<<1, 256, 0, stream>>>(part, nsb);
    k_scan3<<<(n1 + TB - 1) / TB, TB, 0, stream>>>(scn, part, n1, 4 * E);
    k_p1scatter<<<NBLK1, 256, 0, stream>>>(gt_src, gt_dst, at_src, at_dst, scn,
                                           pairs, svals, E, N, Btot);
    k_p2<<<Btot, 256, 0, stream>>>(pairs, svals, scn, rowptr, csr, indeg, norms,
                                   E, N2, Btot);

    // ---- pull passes: 8 nodes/block (2 per wave) ----
    const int pgrid = (N + 7) / 8;
    for (int g = 0; g < 2; ++g) {
        const int* rp = rowptr + g * N;
        float* Q = g ? Qat : Qgt;
        k_pull_sage<<<pgrid, 256, 0, stream>>>((const float4*)h, rp, csr, (float4*)bufA, N);
        k_pull_sage<<<pgrid, 256, 0, stream>>>((const float4*)bufA, rp, csr, (float4*)bufB, N);
        k_pull_q<<<pgrid, 256, 0, stream>>>((const float4*)bufB, rp, csr, norms + g * N,
                                            (float4*)Q, ssum + g * N, N);
    }

    // x = h + LN(x_cat) -> bufA
    k_xcat_ln<<<N / 16, DD, 0, stream>>>(Qgt, Qat, ssum, indeg, Mt, cvec, b3, h,
                                         ln_g, ln_b, bufA, N);
    // ffn1 = relu(x@fW1+fb1) -> bufB
    k_ffn1<<<N / 16, DD, 0, stream>>>(bufA, fW1, fb1, bufB);
    // out = x + LN(ffn1@fW2+fb2)
    k_ffn2_ln_add<<<N / 16, DD, 0, stream>>>(bufB, fW2, fb2, bufA, ln_g, ln_b, (float*)d_out);
}

// Round 5
// 487.347 us; speedup vs baseline: 4.2760x; 1.2784x over previous
//
#include <hip/hip_runtime.h>

#define DD 128
#define NHEAD 8
#define DH 16
#define EPS 1e-5f
#define BSH 9                 // bucket width 512 nodes
#define BWIDTH 512
#define NBLK1 256             // pass-1 blocks

// ---------- bf16 helpers (OCP bf16 = f32 upper half, RNE) ----------
__device__ inline float4 up4(ushort4 u) {
    return make_float4(__uint_as_float((unsigned)u.x << 16),
                       __uint_as_float((unsigned)u.y << 16),
                       __uint_as_float((unsigned)u.z << 16),
                       __uint_as_float((unsigned)u.w << 16));
}
__device__ inline unsigned short f2b(float f) {
    unsigned u = __float_as_uint(f);
    u += 0x7fffu + ((u >> 16) & 1);
    return (unsigned short)(u >> 16);
}

// ================= h -> bf16 copy =================
__global__ void k_h2b(const float4* __restrict__ h4, ushort4* __restrict__ hb, int n4) {
    int i = blockIdx.x * 256 + threadIdx.x;
    if (i < n4) {
        float4 v = h4[i];
        hb[i] = make_ushort4(f2b(v.x), f2b(v.y), f2b(v.z), f2b(v.w));
    }
}

// ================= pass 1a: per-block bucket histograms =================
__global__ __launch_bounds__(256) void k_p1count(
        const int* __restrict__ gs, const int* __restrict__ gd,
        const int* __restrict__ as_, const int* __restrict__ ad,
        int* __restrict__ blkcnt, int E, int N, int Btot) {
    __shared__ int cnts[512];
    for (int j = threadIdx.x; j < 2 * Btot; j += 256) cnts[j] = 0;
    __syncthreads();
    int E2 = 2 * E;
    for (int i = blockIdx.x * 256 + threadIdx.x; i < E2; i += NBLK1 * 256) {
        int g = (i >= E);
        int e = g ? i - E : i;
        int s = g ? as_[e] : gs[e];
        int d = g ? ad[e] : gd[e];
        int cd = d + g * N, cs = s + g * N;
        atomicAdd(&cnts[cd >> BSH], 1);
        atomicAdd(&cnts[Btot + (cs >> BSH)], 1);
    }
    __syncthreads();
    for (int j = threadIdx.x; j < 2 * Btot; j += 256)
        blkcnt[j * NBLK1 + blockIdx.x] = cnts[j];
}

// ================= 3-stage scan =================
__global__ void k_scan1(const int* __restrict__ cnt, int* __restrict__ outv,
                        int* __restrict__ part, int n) {
    __shared__ int wsums[4];
    int t = threadIdx.x;
    int base = blockIdx.x * 1024 + t * 4;
    int v0 = 0, v1 = 0, v2 = 0, v3 = 0;
    if (base + 3 < n) {
        int4 q = *(const int4*)(cnt + base);
        v0 = q.x; v1 = q.y; v2 = q.z; v3 = q.w;
    } else {
        if (base < n)     v0 = cnt[base];
        if (base + 1 < n) v1 = cnt[base + 1];
        if (base + 2 < n) v2 = cnt[base + 2];
        if (base + 3 < n) v3 = cnt[base + 3];
    }
    int s0 = v0, s1 = s0 + v1, s2 = s1 + v2, s3 = s2 + v3;
    int x = s3;
    int lane = t & 63, w = t >> 6;
    for (int o = 1; o < 64; o <<= 1) { int u = __shfl_up(x, o); if (lane >= o) x += u; }
    if (lane == 63) wsums[w] = x;
    __syncthreads();
    int wo = 0;
    for (int i = 0; i < w; ++i) wo += wsums[i];
    int excl = wo + x - s3;
    if (base < n)     outv[base]     = excl;
    if (base + 1 < n) outv[base + 1] = excl + s0;
    if (base + 2 < n) outv[base + 2] = excl + s1;
    if (base + 3 < n) outv[base + 3] = excl + s2;
    if (t == 255) part[blockIdx.x] = wo + x;
}

__global__ void k_scan2(int* __restrict__ part, int nb) {
    __shared__ int ws[4];
    int t = threadIdx.x;
    int v = (t < nb) ? part[t] : 0;
    int x = v;
    int lane = t & 63, w = t >> 6;
    for (int o = 1; o < 64; o <<= 1) { int u = __shfl_up(x, o); if (lane >= o) x += u; }
    if (lane == 63) ws[w] = x;
    __syncthreads();
    int wo = 0;
    for (int i = 0; i < w; ++i) wo += ws[i];
    if (t < nb) part[t] = wo + x - v;
}

__global__ void k_scan3(int* __restrict__ outv, const int* __restrict__ part, int n, int total) {
    int i = blockIdx.x * blockDim.x + threadIdx.x;
    if (i < n) outv[i] += part[i >> 10];
    if (i == 0) outv[n] = total;
}

// ================= pass 1b: scatter edges into bucket regions =================
__global__ __launch_bounds__(256) void k_p1scatter(
        const int* __restrict__ gs, const int* __restrict__ gd,
        const int* __restrict__ as_, const int* __restrict__ ad,
        const int* __restrict__ scn, int2* __restrict__ pairs, int* __restrict__ svals,
        int E, int N, int Btot) {
    __shared__ int cur[512];
    for (int j = threadIdx.x; j < 2 * Btot; j += 256)
        cur[j] = scn[j * NBLK1 + blockIdx.x];
    __syncthreads();
    int E2 = 2 * E;
    for (int i = blockIdx.x * 256 + threadIdx.x; i < E2; i += NBLK1 * 256) {
        int g = (i >= E);
        int e = g ? i - E : i;
        int s = g ? as_[e] : gs[e];
        int d = g ? ad[e] : gd[e];
        int cd = d + g * N, cs = s + g * N;
        int pd = atomicAdd(&cur[cd >> BSH], 1);
        pairs[pd] = make_int2(cd, s);
        int ps = atomicAdd(&cur[Btot + (cs >> BSH)], 1);
        svals[ps - E2] = cs;
    }
}

// ================= pass 2: per-bucket CSR + indeg + norms =================
__global__ __launch_bounds__(256) void k_p2(
        const int2* __restrict__ pairs, const int* __restrict__ svals,
        const int* __restrict__ scn, int* __restrict__ rowptr, int* __restrict__ csr,
        float* __restrict__ indeg, float* __restrict__ norms,
        int E, int N2, int Btot) {
    __shared__ int hist[BWIDTH];
    __shared__ int offs[BWIDTH];
    __shared__ int cur[BWIDTH];
    __shared__ int ws4[4];
    int b = blockIdx.x, t = threadIdx.x;
    int node0 = b << BSH;
    int W = N2 - node0; if (W > BWIDTH) W = BWIDTH;
    int Sd = scn[b * NBLK1], Ed = scn[(b + 1) * NBLK1];
    hist[t] = 0; hist[t + 256] = 0;
    __syncthreads();
    for (int i = Sd + t; i < Ed; i += 256) {
        int2 p = pairs[i];
        atomicAdd(&hist[p.x - node0], 1);
    }
    __syncthreads();
    int a0 = hist[2 * t], a1 = hist[2 * t + 1];
    int sum2 = a0 + a1;
    int lane = t & 63, w = t >> 6;
    int x = sum2;
    for (int o = 1; o < 64; o <<= 1) { int u = __shfl_up(x, o); if (lane >= o) x += u; }
    if (lane == 63) ws4[w] = x;
    __syncthreads();
    int wo = 0;
    for (int i = 0; i < w; ++i) wo += ws4[i];
    int excl2 = wo + x - sum2;
    offs[2 * t] = excl2; offs[2 * t + 1] = excl2 + a0;
    cur[t] = 0; cur[t + 256] = 0;
    __syncthreads();
    for (int j = t; j < W; j += 256) {
        rowptr[node0 + j] = Sd + offs[j];
        indeg[node0 + j] = (float)hist[j];
    }
    if (b == 0 && t == 0) rowptr[N2] = 2 * E;
    for (int i = Sd + t; i < Ed; i += 256) {
        int2 p = pairs[i];
        int l = p.x - node0;
        int pos = atomicAdd(&cur[l], 1);
        csr[Sd + offs[l] + pos] = p.y;
    }
    __syncthreads();
    hist[t] = 0; hist[t + 256] = 0;
    __syncthreads();
    int Ss = scn[(Btot + b) * NBLK1] - 2 * E;
    int Es = scn[(Btot + b + 1) * NBLK1] - 2 * E;
    for (int i = Ss + t; i < Es; i += 256)
        atomicAdd(&hist[svals[i] - node0], 1);
    __syncthreads();
    for (int j = t; j < W; j += 256) {
        int od = hist[j];
        norms[node0 + j] = od > 0 ? rsqrtf((float)od) : 0.f;
    }
}

// ================= pull: avg (SAGE) over bf16 rows, optional norm-scale on output ========
__global__ __launch_bounds__(256) void k_pull_avg(
        const ushort4* __restrict__ xb, const int* __restrict__ rowptr,
        const int* __restrict__ csr, const float* __restrict__ norm_s,
        ushort4* __restrict__ outb, int N, int doscale) {
    int node = blockIdx.x * 8 + (threadIdx.x >> 5);
    int lane = threadIdx.x & 31;
    if (node >= N) return;
    int beg = rowptr[node], end = rowptr[node + 1];
    float4 a = up4(xb[(size_t)node * 32 + lane]);          // self term
    int e = beg;
    while (e < end) {
        int nb = end - e; if (nb > 32) nb = 32;
        int idx = (lane < nb) ? csr[e + lane] : 0;
        #pragma unroll 4
        for (int d = 0; d < nb; ++d) {
            int s = __shfl(idx, d, 32);
            float4 v = up4(xb[(size_t)s * 32 + lane]);
            a.x += v.x; a.y += v.y; a.z += v.z; a.w += v.w;
        }
        e += nb;
    }
    float sc = 1.f / (float)(end - beg + 1);
    if (doscale) sc *= norm_s[node];
    outb[(size_t)node * 32 + lane] =
        make_ushort4(f2b(a.x * sc), f2b(a.y * sc), f2b(a.z * sc), f2b(a.w * sc));
}

// ================= pull: plain sum of pre-scaled bf16 rows -> f32 Q, + ssum =================
__global__ __launch_bounds__(256) void k_pull3(
        const ushort4* __restrict__ Pb, const int* __restrict__ rowptr,
        const int* __restrict__ csr, const float* __restrict__ norm_s,
        float4* __restrict__ Q, float* __restrict__ ssum, int N) {
    int node = blockIdx.x * 8 + (threadIdx.x >> 5);
    int lane = threadIdx.x & 31;
    if (node >= N) return;
    int beg = rowptr[node], end = rowptr[node + 1];
    float4 a = make_float4(0.f, 0.f, 0.f, 0.f);
    float ss = 0.f;
    int e = beg;
    while (e < end) {
        int nb = end - e; if (nb > 32) nb = 32;
        int idx = (lane < nb) ? csr[e + lane] : 0;
        #pragma unroll 4
        for (int d = 0; d < nb; ++d) {
            int s = __shfl(idx, d, 32);
            float4 v = up4(Pb[(size_t)s * 32 + lane]);
            a.x += v.x; a.y += v.y; a.z += v.z; a.w += v.w;
            ss += norm_s[s];
        }
        e += nb;
    }
    Q[(size_t)node * 32 + lane] = a;
    if (lane == 0) ssum[node] = ss;
}

// ================= weight pre-combination =================
__global__ void k_wcomb(const float* __restrict__ A, const float* __restrict__ B,
                        float* __restrict__ C) {          // C[i] = A[i](128x128) @ B[i](128x16)
    int i = blockIdx.x;
    const float* Ai = A + (size_t)i * DD * DD;
    const float* Bi = B + (size_t)i * DD * DH;
    float* Ci = C + (size_t)i * DD * DH;
    for (int o = threadIdx.x; o < DD * DH; o += blockDim.x) {
        int r = o >> 4, c = o & 15;
        float acc = 0.f;
        #pragma unroll 8
        for (int k = 0; k < DD; ++k) acc += Ai[r * DD + k] * Bi[k * DH + c];
        Ci[o] = acc;
    }
}

// transposed variant: Mt[k][head*16+c] = (A[i] @ B[i])[k][c]
__global__ void k_wcombT(const float* __restrict__ A, const float* __restrict__ B,
                         float* __restrict__ Mt) {
    int i = blockIdx.x;
    const float* Ai = A + (size_t)i * DD * DD;
    const float* Bi = B + (size_t)i * DD * DH;
    for (int o = threadIdx.x; o < DD * DH; o += blockDim.x) {
        int r = o >> 4, c = o & 15;
        float acc = 0.f;
        #pragma unroll 8
        for (int k = 0; k < DD; ++k) acc += Ai[r * DD + k] * Bi[k * DH + c];
        Mt[r * DD + i * DH + c] = acc;
    }
}

__global__ void k_cvec(const float* __restrict__ b1, const float* __restrict__ b2,
                       const float* __restrict__ T, const float* __restrict__ W3,
                       float* __restrict__ cvec) {
    int idx = blockIdx.x * blockDim.x + threadIdx.x;
    if (idx >= NHEAD * DH) return;
    int i = idx >> 4, c = idx & 15;
    float acc = 0.f;
    for (int k = 0; k < DD; ++k)
        acc += b1[i * DD + k] * T[(size_t)i * DD * DH + k * DH + c]
             + b2[i * DD + k] * W3[(size_t)i * DD * DH + k * DH + c];
    cvec[idx] = acc;
}

// ================= fused tail: x = h + LN(xcat); f1 = relu(x@W1+b1); out = x + LN(f1@W2+b2)
// 256 threads = 4 waves; 16 rows/block, 4 rows/wave; lane owns cols (l, l+64).
__global__ __launch_bounds__(256) void k_tail(
        const float4* __restrict__ Qgt4, const float4* __restrict__ Qat4,
        const float* __restrict__ ssum, const float* __restrict__ indeg,
        const float* __restrict__ Mt, const float* __restrict__ cvec,
        const float* __restrict__ b3, const float* __restrict__ h,
        const float* __restrict__ ln_g, const float* __restrict__ ln_b,
        const float* __restrict__ fW1, const float* __restrict__ Fb1,
        const float* __restrict__ fW2, const float* __restrict__ Fb2,
        float* __restrict__ out, int N) {
    __shared__ float qs[2][16][DD];
    __shared__ float xs[16][DD];
    __shared__ float f1s[16][DD];
    int t = threadIdx.x;
    int w = t >> 6, l = t & 63;
    int w4 = w * 4;
    int row0 = blockIdx.x * 16;
    {   // stage Q tiles (512 float4 each)
        const float4* s0 = Qgt4 + (size_t)row0 * 32;
        const float4* s1 = Qat4 + (size_t)row0 * 32;
        float4* d0 = (float4*)&qs[0][0][0];
        float4* d1 = (float4*)&qs[1][0][0];
        d0[t] = s0[t]; d0[t + 256] = s0[t + 256];
        d1[t] = s1[t]; d1[t + 256] = s1[t + 256];
    }
    __syncthreads();
    int g = l >> 5;
    int j0 = l, j1 = l + 64;
    float cv0 = cvec[(j0 >> 4) * DH + (j0 & 15)], cv1 = cvec[(j1 >> 4) * DH + (j1 & 15)];
    float b30 = b3[(j0 >> 4) * DH + (j0 & 15)],  b31 = b3[(j1 >> 4) * DH + (j1 & 15)];
    float gl0 = ln_g[j0], gl1 = ln_g[j1], bl0 = ln_b[j0], bl1 = ln_b[j1];

    // ---- GEMM1: xcat = Q_g @ M ----
    float a0[4] = {0.f, 0.f, 0.f, 0.f}, a1[4] = {0.f, 0.f, 0.f, 0.f};
    const float* qb = &qs[g][w4][0];
    #pragma unroll 2
    for (int k = 0; k < DD; ++k) {
        float m0 = Mt[k * DD + j0], m1 = Mt[k * DD + j1];
        #pragma unroll
        for (int r = 0; r < 4; ++r) {
            float qk = qb[r * DD + k];
            a0[r] += qk * m0; a1[r] += qk * m1;
        }
    }
    // ---- epilogue1 + LN + residual ----
    float x0r[4], x1r[4];
    #pragma unroll
    for (int r = 0; r < 4; ++r) {
        int row = row0 + w4 + r;
        float ss = ssum[g * N + row];
        float id = indeg[g * N + row];
        float nd = id > 0.f ? rsqrtf(id) : 0.f;
        float v0 = (a0[r] + ss * cv0) * nd + b30;
        float v1 = (a1[r] + ss * cv1) * nd + b31;
        float s = v0 + v1, s2 = v0 * v0 + v1 * v1;
        for (int o = 32; o > 0; o >>= 1) { s += __shfl_xor(s, o); s2 += __shfl_xor(s2, o); }
        float mu = s * (1.f / DD);
        float var = s2 * (1.f / DD) - mu * mu;
        float rs = rsqrtf(var + EPS);
        float x0 = h[(size_t)row * DD + j0] + (v0 - mu) * rs * gl0 + bl0;
        float x1 = h[(size_t)row * DD + j1] + (v1 - mu) * rs * gl1 + bl1;
        x0r[r] = x0; x1r[r] = x1;
        xs[w4 + r][j0] = x0; xs[w4 + r][j1] = x1;    // intra-wave transpose (no barrier)
    }
    // ---- GEMM2: f1 = relu(x @ fW1 + Fb1) ----
    float c0[4] = {0.f, 0.f, 0.f, 0.f}, c1[4] = {0.f, 0.f, 0.f, 0.f};
    #pragma unroll 2
    for (int k = 0; k < DD; ++k) {
        float w0 = fW1[k * DD + j0], w1 = fW1[k * DD + j1];
        #pragma unroll
        for (int r = 0; r < 4; ++r) {
            float xk = xs[w4 + r][k];
            c0[r] += xk * w0; c1[r] += xk * w1;
        }
    }
    float fb0 = Fb1[j0], fb1v = Fb1[j1];
    #pragma unroll
    for (int r = 0; r < 4; ++r) {
        float v0 = c0[r] + fb0, v1 = c1[r] + fb1v;
        f1s[w4 + r][j0] = v0 > 0.f ? v0 : 0.f;
        f1s[w4 + r][j1] = v1 > 0.f ? v1 : 0.f;
    }
    // ---- GEMM3: out = x + LN(f1 @ fW2 + Fb2) ----
    float d0[4] = {0.f, 0.f, 0.f, 0.f}, d1[4] = {0.f, 0.f, 0.f, 0.f};
    #pragma unroll 2
    for (int k = 0; k < DD; ++k) {
        float w0 = fW2[k * DD + j0], w1 = fW2[k * DD + j1];
        #pragma unroll
        for (int r = 0; r < 4; ++r) {
            float fk = f1s[w4 + r][k];
            d0[r] += fk * w0; d1[r] += fk * w1;
        }
    }
    float gb0 = Fb2[j0], gb1 = Fb2[j1];
    #pragma unroll
    for (int r = 0; r < 4; ++r) {
        int row = row0 + w4 + r;
        float v0 = d0[r] + gb0, v1 = d1[r] + gb1;
        float s = v0 + v1, s2 = v0 * v0 + v1 * v1;
        for (int o = 32; o > 0; o >>= 1) { s += __shfl_xor(s, o); s2 += __shfl_xor(s2, o); }
        float mu = s * (1.f / DD);
        float var = s2 * (1.f / DD) - mu * mu;
        float rs = rsqrtf(var + EPS);
        out[(size_t)row * DD + j0] = x0r[r] + (v0 - mu) * rs * gl0 + bl0;
        out[(size_t)row * DD + j1] = x1r[r] + (v1 - mu) * rs * gl1 + bl1;
    }
}

extern "C" void kernel_launch(void* const* d_in, const int* in_sizes, int n_in,
                              void* d_out, int out_size, void* d_ws, size_t ws_size,
                              hipStream_t stream) {
    const float* h      = (const float*)d_in[0];
    const int*   gt_src = (const int*)d_in[1];
    const int*   gt_dst = (const int*)d_in[2];
    const int*   at_src = (const int*)d_in[3];
    const int*   at_dst = (const int*)d_in[4];
    const float* W1     = (const float*)d_in[5];
    const float* b1     = (const float*)d_in[6];
    const float* W2     = (const float*)d_in[7];
    const float* b2     = (const float*)d_in[8];
    const float* W3     = (const float*)d_in[9];
    const float* b3     = (const float*)d_in[10];
    const float* fW1    = (const float*)d_in[11];
    const float* fb1    = (const float*)d_in[12];
    const float* fW2    = (const float*)d_in[13];
    const float* fb2    = (const float*)d_in[14];
    const float* ln_g   = (const float*)d_in[15];
    const float* ln_b   = (const float*)d_in[16];

    const int E = in_sizes[1];
    const int N = in_sizes[0] / DD;
    const size_t NB = (size_t)N * DD;
    const int N2 = 2 * N;
    const int Btot = (N2 + BWIDTH - 1) >> BSH;
    const int n1 = 2 * Btot * NBLK1;

    // ---- workspace layout ----
    float* w = (float*)d_ws;
    float* Qgt = w;                              // NB f32 (25.6 MB)
    unsigned short* hb    = (unsigned short*)(Qgt + NB);   // NB bf16
    unsigned short* bufAb = hb + NB;                       // NB bf16
    unsigned short* bufBb = bufAb + NB;                    // NB bf16
    float* sm = (float*)(bufBb + NB);
    float* norms = sm;  sm += N2;
    float* indeg = sm;  sm += N2;
    float* ssum  = sm;  sm += N2;
    float* Tm    = sm;  sm += (size_t)NHEAD * DD * DH;
    float* Mt    = sm;  sm += DD * DD;
    float* cvec  = sm;  sm += NHEAD * DH + 32;
    int* ip = (int*)sm;
    int* rowptr = ip;  ip += ((N2 + 1 + 3) & ~3);
    int* csr    = ip;  ip += 2 * E;
    int* blkcnt = ip;  ip += ((n1 + 1 + 3) & ~3);
    int* scn    = ip;  ip += ((n1 + 1 + 3) & ~3);
    int* part   = ip;  ip += 256;
    // CSR-build scratch aliased over Qgt (written only later, in pass 3)
    int2* pairs = (int2*)Qgt;                    // 2E int2 = 9.6 MB
    int*  svals = (int*)(pairs + 2 * E);         // 2E int  = 4.8 MB
    float* Qat  = (float*)d_out;                 // reuse d_out; overwritten by k_tail

    // weight pre-combination
    k_wcomb <<<NHEAD, 256, 0, stream>>>(W2, W3, Tm);
    k_wcombT<<<NHEAD, 256, 0, stream>>>(W1, Tm, Mt);
    k_cvec  <<<1, 128, 0, stream>>>(b1, b2, Tm, W3, cvec);

    const int TB = 256;
    // h -> bf16
    k_h2b<<<(int)(NB / 4 + TB - 1) / TB, TB, 0, stream>>>((const float4*)h, (ushort4*)hb,
                                                          (int)(NB / 4));
    // CSR build (no global atomics)
    k_p1count<<<NBLK1, 256, 0, stream>>>(gt_src, gt_dst, at_src, at_dst, blkcnt, E, N, Btot);
    int nsb = (n1 + 1023) / 1024;
    k_scan1<<<nsb, 256, 0, stream>>>(blkcnt, scn, part, n1);
    k_scan2<<<1, 256, 0, stream>>>(part, nsb);
    k_scan3<<<(n1 + TB - 1) / TB, TB, 0, stream>>>(scn, part, n1, 4 * E);
    k_p1scatter<<<NBLK1, 256, 0, stream>>>(gt_src, gt_dst, at_src, at_dst, scn,
                                           pairs, svals, E, N, Btot);
    k_p2<<<Btot, 256, 0, stream>>>(pairs, svals, scn, rowptr, csr, indeg, norms,
                                   E, N2, Btot);

    // pull passes (bf16 gathers): 8 nodes/block
    const int pgrid = (N + 7) / 8;
    for (int g = 0; g < 2; ++g) {
        const int* rp = rowptr + g * N;
        const float* ns = norms + g * N;
        float* Q = g ? Qat : Qgt;
        k_pull_avg<<<pgrid, 256, 0, stream>>>((const ushort4*)hb, rp, csr, ns,
                                              (ushort4*)bufAb, N, 0);
        k_pull_avg<<<pgrid, 256, 0, stream>>>((const ushort4*)bufAb, rp, csr, ns,
                                              (ushort4*)bufBb, N, 1);
        k_pull3<<<pgrid, 256, 0, stream>>>((const ushort4*)bufBb, rp, csr, ns,
                                           (float4*)Q, ssum + g * N, N);
    }

    // fused dense tail
    k_tail<<<N / 16, 256, 0, stream>>>((const float4*)Qgt, (const float4*)Qat, ssum, indeg,
                                       Mt, cvec, b3, h, ln_g, ln_b,
                                       fW1, fb1, fW2, fb2, (float*)d_out, N);
}

// Round 6
// 439.421 us; speedup vs baseline: 4.7424x; 1.1091x over previous
//
#include <hip/hip_runtime.h>

#define DD 128
#define NHEAD 8
#define DH 16
#define EPS 1e-5f
#define BSH 9                 // bucket width 512 nodes
#define BWIDTH 512
#define NBLK1 256             // pass-1 blocks

// ---------- bf16 helpers (OCP bf16 = f32 upper half, RNE) ----------
__device__ inline float4 up4(ushort4 u) {
    return make_float4(__uint_as_float((unsigned)u.x << 16),
                       __uint_as_float((unsigned)u.y << 16),
                       __uint_as_float((unsigned)u.z << 16),
                       __uint_as_float((unsigned)u.w << 16));
}
__device__ inline unsigned short f2b(float f) {
    unsigned u = __float_as_uint(f);
    u += 0x7fffu + ((u >> 16) & 1);
    return (unsigned short)(u >> 16);
}

// ================= h -> bf16 copy =================
__global__ void k_h2b(const float4* __restrict__ h4, ushort4* __restrict__ hb, int n4) {
    int i = blockIdx.x * 256 + threadIdx.x;
    if (i < n4) {
        float4 v = h4[i];
        hb[i] = make_ushort4(f2b(v.x), f2b(v.y), f2b(v.z), f2b(v.w));
    }
}

// ================= pass 1a: per-block bucket histograms =================
__global__ __launch_bounds__(256) void k_p1count(
        const int* __restrict__ gs, const int* __restrict__ gd,
        const int* __restrict__ as_, const int* __restrict__ ad,
        int* __restrict__ blkcnt, int E, int N, int Btot) {
    __shared__ int cnts[512];
    for (int j = threadIdx.x; j < 2 * Btot; j += 256) cnts[j] = 0;
    __syncthreads();
    int E2 = 2 * E;
    for (int i = blockIdx.x * 256 + threadIdx.x; i < E2; i += NBLK1 * 256) {
        int g = (i >= E);
        int e = g ? i - E : i;
        int s = g ? as_[e] : gs[e];
        int d = g ? ad[e] : gd[e];
        int cd = d + g * N, cs = s + g * N;
        atomicAdd(&cnts[cd >> BSH], 1);
        atomicAdd(&cnts[Btot + (cs >> BSH)], 1);
    }
    __syncthreads();
    for (int j = threadIdx.x; j < 2 * Btot; j += 256)
        blkcnt[j * NBLK1 + blockIdx.x] = cnts[j];
}

// ================= 3-stage scan =================
__global__ void k_scan1(const int* __restrict__ cnt, int* __restrict__ outv,
                        int* __restrict__ part, int n) {
    __shared__ int wsums[4];
    int t = threadIdx.x;
    int base = blockIdx.x * 1024 + t * 4;
    int v0 = 0, v1 = 0, v2 = 0, v3 = 0;
    if (base + 3 < n) {
        int4 q = *(const int4*)(cnt + base);
        v0 = q.x; v1 = q.y; v2 = q.z; v3 = q.w;
    } else {
        if (base < n)     v0 = cnt[base];
        if (base + 1 < n) v1 = cnt[base + 1];
        if (base + 2 < n) v2 = cnt[base + 2];
        if (base + 3 < n) v3 = cnt[base + 3];
    }
    int s0 = v0, s1 = s0 + v1, s2 = s1 + v2, s3 = s2 + v3;
    int x = s3;
    int lane = t & 63, w = t >> 6;
    for (int o = 1; o < 64; o <<= 1) { int u = __shfl_up(x, o); if (lane >= o) x += u; }
    if (lane == 63) wsums[w] = x;
    __syncthreads();
    int wo = 0;
    for (int i = 0; i < w; ++i) wo += wsums[i];
    int excl = wo + x - s3;
    if (base < n)     outv[base]     = excl;
    if (base + 1 < n) outv[base + 1] = excl + s0;
    if (base + 2 < n) outv[base + 2] = excl + s1;
    if (base + 3 < n) outv[base + 3] = excl + s2;
    if (t == 255) part[blockIdx.x] = wo + x;
}

__global__ void k_scan2(int* __restrict__ part, int nb) {
    __shared__ int ws[4];
    int t = threadIdx.x;
    int v = (t < nb) ? part[t] : 0;
    int x = v;
    int lane = t & 63, w = t >> 6;
    for (int o = 1; o < 64; o <<= 1) { int u = __shfl_up(x, o); if (lane >= o) x += u; }
    if (lane == 63) ws[w] = x;
    __syncthreads();
    int wo = 0;
    for (int i = 0; i < w; ++i) wo += ws[i];
    if (t < nb) part[t] = wo + x - v;
}

__global__ void k_scan3(int* __restrict__ outv, const int* __restrict__ part, int n, int total) {
    int i = blockIdx.x * blockDim.x + threadIdx.x;
    if (i < n) outv[i] += part[i >> 10];
    if (i == 0) outv[n] = total;
}

// ================= pass 1b: scatter edges into bucket regions =================
__global__ __launch_bounds__(256) void k_p1scatter(
        const int* __restrict__ gs, const int* __restrict__ gd,
        const int* __restrict__ as_, const int* __restrict__ ad,
        const int* __restrict__ scn, int2* __restrict__ pairs, int* __restrict__ svals,
        int E, int N, int Btot) {
    __shared__ int cur[512];
    for (int j = threadIdx.x; j < 2 * Btot; j += 256)
        cur[j] = scn[j * NBLK1 + blockIdx.x];
    __syncthreads();
    int E2 = 2 * E;
    for (int i = blockIdx.x * 256 + threadIdx.x; i < E2; i += NBLK1 * 256) {
        int g = (i >= E);
        int e = g ? i - E : i;
        int s = g ? as_[e] : gs[e];
        int d = g ? ad[e] : gd[e];
        int cd = d + g * N, cs = s + g * N;
        int pd = atomicAdd(&cur[cd >> BSH], 1);
        pairs[pd] = make_int2(cd, s);
        int ps = atomicAdd(&cur[Btot + (cs >> BSH)], 1);
        svals[ps - E2] = cs;
    }
}

// ================= pass 2: per-bucket CSR + indeg + norms =================
__global__ __launch_bounds__(256) void k_p2(
        const int2* __restrict__ pairs, const int* __restrict__ svals,
        const int* __restrict__ scn, int* __restrict__ rowptr, int* __restrict__ csr,
        float* __restrict__ indeg, float* __restrict__ norms,
        int E, int N2, int Btot) {
    __shared__ int hist[BWIDTH];
    __shared__ int offs[BWIDTH];
    __shared__ int cur[BWIDTH];
    __shared__ int ws4[4];
    int b = blockIdx.x, t = threadIdx.x;
    int node0 = b << BSH;
    int W = N2 - node0; if (W > BWIDTH) W = BWIDTH;
    int Sd = scn[b * NBLK1], Ed = scn[(b + 1) * NBLK1];
    hist[t] = 0; hist[t + 256] = 0;
    __syncthreads();
    for (int i = Sd + t; i < Ed; i += 256) {
        int2 p = pairs[i];
        atomicAdd(&hist[p.x - node0], 1);
    }
    __syncthreads();
    int a0 = hist[2 * t], a1 = hist[2 * t + 1];
    int sum2 = a0 + a1;
    int lane = t & 63, w = t >> 6;
    int x = sum2;
    for (int o = 1; o < 64; o <<= 1) { int u = __shfl_up(x, o); if (lane >= o) x += u; }
    if (lane == 63) ws4[w] = x;
    __syncthreads();
    int wo = 0;
    for (int i = 0; i < w; ++i) wo += ws4[i];
    int excl2 = wo + x - sum2;
    offs[2 * t] = excl2; offs[2 * t + 1] = excl2 + a0;
    cur[t] = 0; cur[t + 256] = 0;
    __syncthreads();
    for (int j = t; j < W; j += 256) {
        rowptr[node0 + j] = Sd + offs[j];
        indeg[node0 + j] = (float)hist[j];
    }
    if (b == 0 && t == 0) rowptr[N2] = 2 * E;
    for (int i = Sd + t; i < Ed; i += 256) {
        int2 p = pairs[i];
        int l = p.x - node0;
        int pos = atomicAdd(&cur[l], 1);
        csr[Sd + offs[l] + pos] = p.y;
    }
    __syncthreads();
    hist[t] = 0; hist[t + 256] = 0;
    __syncthreads();
    int Ss = scn[(Btot + b) * NBLK1] - 2 * E;
    int Es = scn[(Btot + b + 1) * NBLK1] - 2 * E;
    for (int i = Ss + t; i < Es; i += 256)
        atomicAdd(&hist[svals[i] - node0], 1);
    __syncthreads();
    for (int j = t; j < W; j += 256) {
        int od = hist[j];
        norms[node0 + j] = od > 0 ? rsqrtf((float)od) : 0.f;
    }
}

// ================= pull: avg (SAGE) over bf16 rows, optional norm-scale on output ========
__global__ __launch_bounds__(256) void k_pull_avg(
        const ushort4* __restrict__ xb, const int* __restrict__ rowptr,
        const int* __restrict__ csr, const float* __restrict__ norm_s,
        ushort4* __restrict__ outb, int N, int doscale) {
    int node = blockIdx.x * 8 + (threadIdx.x >> 5);
    int lane = threadIdx.x & 31;
    if (node >= N) return;
    int beg = rowptr[node], end = rowptr[node + 1];
    float4 a = up4(xb[(size_t)node * 32 + lane]);          // self term
    int e = beg;
    while (e < end) {
        int nb = end - e; if (nb > 32) nb = 32;
        int idx = (lane < nb) ? csr[e + lane] : 0;
        #pragma unroll 4
        for (int d = 0; d < nb; ++d) {
            int s = __shfl(idx, d, 32);
            float4 v = up4(xb[(size_t)s * 32 + lane]);
            a.x += v.x; a.y += v.y; a.z += v.z; a.w += v.w;
        }
        e += nb;
    }
    float sc = 1.f / (float)(end - beg + 1);
    if (doscale) sc *= norm_s[node];
    outb[(size_t)node * 32 + lane] =
        make_ushort4(f2b(a.x * sc), f2b(a.y * sc), f2b(a.z * sc), f2b(a.w * sc));
}

// ================= pull: plain sum of pre-scaled bf16 rows -> f32 Q, + ssum =================
__global__ __launch_bounds__(256) void k_pull3(
        const ushort4* __restrict__ Pb, const int* __restrict__ rowptr,
        const int* __restrict__ csr, const float* __restrict__ norm_s,
        float4* __restrict__ Q, float* __restrict__ ssum, int N) {
    int node = blockIdx.x * 8 + (threadIdx.x >> 5);
    int lane = threadIdx.x & 31;
    if (node >= N) return;
    int beg = rowptr[node], end = rowptr[node + 1];
    float4 a = make_float4(0.f, 0.f, 0.f, 0.f);
    float ss = 0.f;
    int e = beg;
    while (e < end) {
        int nb = end - e; if (nb > 32) nb = 32;
        int idx = (lane < nb) ? csr[e + lane] : 0;
        #pragma unroll 4
        for (int d = 0; d < nb; ++d) {
            int s = __shfl(idx, d, 32);
            float4 v = up4(Pb[(size_t)s * 32 + lane]);
            a.x += v.x; a.y += v.y; a.z += v.z; a.w += v.w;
            ss += norm_s[s];
        }
        e += nb;
    }
    Q[(size_t)node * 32 + lane] = a;
    if (lane == 0) ssum[node] = ss;
}

// ================= weight pre-combination =================
__global__ void k_wcomb(const float* __restrict__ A, const float* __restrict__ B,
                        float* __restrict__ C) {          // C[i] = A[i](128x128) @ B[i](128x16)
    int i = blockIdx.x;
    const float* Ai = A + (size_t)i * DD * DD;
    const float* Bi = B + (size_t)i * DD * DH;
    float* Ci = C + (size_t)i * DD * DH;
    for (int o = threadIdx.x; o < DD * DH; o += blockDim.x) {
        int r = o >> 4, c = o & 15;
        float acc = 0.f;
        #pragma unroll 8
        for (int k = 0; k < DD; ++k) acc += Ai[r * DD + k] * Bi[k * DH + c];
        Ci[o] = acc;
    }
}

// transposed variant: Mt[k][head*16+c] = (A[i] @ B[i])[k][c]
__global__ void k_wcombT(const float* __restrict__ A, const float* __restrict__ B,
                         float* __restrict__ Mt) {
    int i = blockIdx.x;
    const float* Ai = A + (size_t)i * DD * DD;
    const float* Bi = B + (size_t)i * DD * DH;
    for (int o = threadIdx.x; o < DD * DH; o += blockDim.x) {
        int r = o >> 4, c = o & 15;
        float acc = 0.f;
        #pragma unroll 8
        for (int k = 0; k < DD; ++k) acc += Ai[r * DD + k] * Bi[k * DH + c];
        Mt[r * DD + i * DH + c] = acc;
    }
}

__global__ void k_cvec(const float* __restrict__ b1, const float* __restrict__ b2,
                       const float* __restrict__ T, const float* __restrict__ W3,
                       float* __restrict__ cvec) {
    int idx = blockIdx.x * blockDim.x + threadIdx.x;
    if (idx >= NHEAD * DH) return;
    int i = idx >> 4, c = idx & 15;
    float acc = 0.f;
    for (int k = 0; k < DD; ++k)
        acc += b1[i * DD + k] * T[(size_t)i * DD * DH + k * DH + c]
             + b2[i * DD + k] * W3[(size_t)i * DD * DH + k * DH + c];
    cvec[idx] = acc;
}

// ================= fused tail, LDS-staged weights =================
// 256 thr = 4 waves; 32 rows/block, 8 rows/wave; lane owns cols (l, l+64).
// LDS: qs[2][32][128] (32K) + xs[32][128] (16K) + ws[32][128] (16K) = 64 KB.
// f1 reuses qs[0] (dead after GEMM1).
__global__ __launch_bounds__(256) void k_tail(
        const float4* __restrict__ Qgt4, const float4* __restrict__ Qat4,
        const float* __restrict__ ssum, const float* __restrict__ indeg,
        const float* __restrict__ Mt, const float* __restrict__ cvec,
        const float* __restrict__ b3, const float* __restrict__ h,
        const float* __restrict__ ln_g, const float* __restrict__ ln_b,
        const float* __restrict__ fW1, const float* __restrict__ Fb1,
        const float* __restrict__ fW2, const float* __restrict__ Fb2,
        float* __restrict__ out, int N) {
    __shared__ float qs[2][32][DD];
    __shared__ float xs[32][DD];
    __shared__ float ws[32][DD];
    int t = threadIdx.x;
    int w = t >> 6, l = t & 63;
    int w8 = w * 8;
    int row0 = blockIdx.x * 32;
    {   // stage Q tiles: 1024 float4 per graph, row-clamped
        float4* d0 = (float4*)&qs[0][0][0];
        float4* d1 = (float4*)&qs[1][0][0];
        #pragma unroll
        for (int i = 0; i < 4; ++i) {
            int idx = t + 256 * i;
            int r = idx >> 5, c = idx & 31;
            int gr = row0 + r; if (gr >= N) gr = N - 1;
            d0[idx] = Qgt4[(size_t)gr * 32 + c];
            d1[idx] = Qat4[(size_t)gr * 32 + c];
        }
    }
    int g = l >> 5;
    int j0 = l, j1 = l + 64;
    float cv0 = cvec[(j0 >> 4) * DH + (j0 & 15)], cv1 = cvec[(j1 >> 4) * DH + (j1 & 15)];
    float b30 = b3[(j0 >> 4) * DH + (j0 & 15)],  b31 = b3[(j1 >> 4) * DH + (j1 & 15)];
    float gl0 = ln_g[j0], gl1 = ln_g[j1], bl0 = ln_b[j0], bl1 = ln_b[j1];

    // ---- GEMM1: xcat = Q_g @ M (weights k-tiled through LDS) ----
    float a0[8] = {0,0,0,0,0,0,0,0}, a1[8] = {0,0,0,0,0,0,0,0};
    const float* qb = &qs[g][w8][0];
    for (int kt = 0; kt < 4; ++kt) {
        __syncthreads();
        const float4* wsrc = (const float4*)(Mt + kt * 32 * DD);
        float4* wdst = (float4*)&ws[0][0];
        #pragma unroll
        for (int i = 0; i < 4; ++i) wdst[t + 256 * i] = wsrc[t + 256 * i];
        __syncthreads();
        #pragma unroll 4
        for (int kk = 0; kk < 32; ++kk) {
            float m0 = ws[kk][j0], m1 = ws[kk][j1];
            #pragma unroll
            for (int r = 0; r < 8; ++r) {
                float qk = qb[r * DD + kt * 32 + kk];
                a0[r] += qk * m0; a1[r] += qk * m1;
            }
        }
    }
    // ---- epilogue1 + LN + residual ----
    float x0r[8], x1r[8];
    #pragma unroll
    for (int r = 0; r < 8; ++r) {
        int row = row0 + w8 + r;
        int rc = row < N ? row : N - 1;
        float ss = ssum[g * N + rc];
        float id = indeg[g * N + rc];
        float nd = id > 0.f ? rsqrtf(id) : 0.f;
        float v0 = (a0[r] + ss * cv0) * nd + b30;
        float v1 = (a1[r] + ss * cv1) * nd + b31;
        float s = v0 + v1, s2 = v0 * v0 + v1 * v1;
        for (int o = 32; o > 0; o >>= 1) { s += __shfl_xor(s, o); s2 += __shfl_xor(s2, o); }
        float mu = s * (1.f / DD);
        float var = s2 * (1.f / DD) - mu * mu;
        float rs = rsqrtf(var + EPS);
        float x0 = h[(size_t)rc * DD + j0] + (v0 - mu) * rs * gl0 + bl0;
        float x1 = h[(size_t)rc * DD + j1] + (v1 - mu) * rs * gl1 + bl1;
        x0r[r] = x0; x1r[r] = x1;
        xs[w8 + r][j0] = x0; xs[w8 + r][j1] = x1;    // intra-wave transpose
    }
    // ---- GEMM2: f1 = relu(x @ fW1 + Fb1), f1 -> qs[0] ----
    float c0[8] = {0,0,0,0,0,0,0,0}, c1[8] = {0,0,0,0,0,0,0,0};
    for (int kt = 0; kt < 4; ++kt) {
        __syncthreads();
        const float4* wsrc = (const float4*)(fW1 + kt * 32 * DD);
        float4* wdst = (float4*)&ws[0][0];
        #pragma unroll
        for (int i = 0; i < 4; ++i) wdst[t + 256 * i] = wsrc[t + 256 * i];
        __syncthreads();
        #pragma unroll 4
        for (int kk = 0; kk < 32; ++kk) {
            float w0 = ws[kk][j0], w1 = ws[kk][j1];
            #pragma unroll
            for (int r = 0; r < 8; ++r) {
                float xk = xs[w8 + r][kt * 32 + kk];
                c0[r] += xk * w0; c1[r] += xk * w1;
            }
        }
    }
    float* f1b = &qs[0][0][0];
    float fb0 = Fb1[j0], fb1v = Fb1[j1];
    #pragma unroll
    for (int r = 0; r < 8; ++r) {
        float v0 = c0[r] + fb0, v1 = c1[r] + fb1v;
        f1b[(w8 + r) * DD + j0] = v0 > 0.f ? v0 : 0.f;
        f1b[(w8 + r) * DD + j1] = v1 > 0.f ? v1 : 0.f;
    }
    // ---- GEMM3: out = x + LN(f1 @ fW2 + Fb2) ----
    float d0[8] = {0,0,0,0,0,0,0,0}, d1[8] = {0,0,0,0,0,0,0,0};
    for (int kt = 0; kt < 4; ++kt) {
        __syncthreads();                     // also orders f1 writes before reads
        const float4* wsrc = (const float4*)(fW2 + kt * 32 * DD);
        float4* wdst = (float4*)&ws[0][0];
        #pragma unroll
        for (int i = 0; i < 4; ++i) wdst[t + 256 * i] = wsrc[t + 256 * i];
        __syncthreads();
        #pragma unroll 4
        for (int kk = 0; kk < 32; ++kk) {
            float w0 = ws[kk][j0], w1 = ws[kk][j1];
            #pragma unroll
            for (int r = 0; r < 8; ++r) {
                float fk = f1b[(w8 + r) * DD + kt * 32 + kk];
                d0[r] += fk * w0; d1[r] += fk * w1;
            }
        }
    }
    float gb0 = Fb2[j0], gb1 = Fb2[j1];
    #pragma unroll
    for (int r = 0; r < 8; ++r) {
        int row = row0 + w8 + r;
        float v0 = d0[r] + gb0, v1 = d1[r] + gb1;
        float s = v0 + v1, s2 = v0 * v0 + v1 * v1;
        for (int o = 32; o > 0; o >>= 1) { s += __shfl_xor(s, o); s2 += __shfl_xor(s2, o); }
        float mu = s * (1.f / DD);
        float var = s2 * (1.f / DD) - mu * mu;
        float rs = rsqrtf(var + EPS);
        if (row < N) {
            out[(size_t)row * DD + j0] = x0r[r] + (v0 - mu) * rs * gl0 + bl0;
            out[(size_t)row * DD + j1] = x1r[r] + (v1 - mu) * rs * gl1 + bl1;
        }
    }
}

extern "C" void kernel_launch(void* const* d_in, const int* in_sizes, int n_in,
                              void* d_out, int out_size, void* d_ws, size_t ws_size,
                              hipStream_t stream) {
    const float* h      = (const float*)d_in[0];
    const int*   gt_src = (const int*)d_in[1];
    const int*   gt_dst = (const int*)d_in[2];
    const int*   at_src = (const int*)d_in[3];
    const int*   at_dst = (const int*)d_in[4];
    const float* W1     = (const float*)d_in[5];
    const float* b1     = (const float*)d_in[6];
    const float* W2     = (const float*)d_in[7];
    const float* b2     = (const float*)d_in[8];
    const float* W3     = (const float*)d_in[9];
    const float* b3     = (const float*)d_in[10];
    const float* fW1    = (const float*)d_in[11];
    const float* fb1    = (const float*)d_in[12];
    const float* fW2    = (const float*)d_in[13];
    const float* fb2    = (const float*)d_in[14];
    const float* ln_g   = (const float*)d_in[15];
    const float* ln_b   = (const float*)d_in[16];

    const int E = in_sizes[1];
    const int N = in_sizes[0] / DD;
    const size_t NB = (size_t)N * DD;
    const int N2 = 2 * N;
    const int Btot = (N2 + BWIDTH - 1) >> BSH;
    const int n1 = 2 * Btot * NBLK1;

    // ---- workspace layout ----
    float* w = (float*)d_ws;
    float* Qgt = w;                              // NB f32 (25.6 MB)
    unsigned short* hb    = (unsigned short*)(Qgt + NB);   // NB bf16
    unsigned short* bufAb = hb + NB;                       // NB bf16
    unsigned short* bufBb = bufAb + NB;                    // NB bf16
    float* sm = (float*)(bufBb + NB);
    float* norms = sm;  sm += N2;
    float* indeg = sm;  sm += N2;
    float* ssum  = sm;  sm += N2;
    float* Tm    = sm;  sm += (size_t)NHEAD * DD * DH;
    float* Mt    = sm;  sm += DD * DD;
    float* cvec  = sm;  sm += NHEAD * DH + 32;
    int* ip = (int*)sm;
    int* rowptr = ip;  ip += ((N2 + 1 + 3) & ~3);
    int* csr    = ip;  ip += 2 * E;
    int* blkcnt = ip;  ip += ((n1 + 1 + 3) & ~3);
    int* scn    = ip;  ip += ((n1 + 1 + 3) & ~3);
    int* part   = ip;  ip += 256;
    // CSR-build scratch aliased over Qgt (written only later, in pass 3)
    int2* pairs = (int2*)Qgt;                    // 2E int2 = 9.6 MB
    int*  svals = (int*)(pairs + 2 * E);         // 2E int  = 4.8 MB
    float* Qat  = (float*)d_out;                 // reuse d_out; overwritten by k_tail

    // weight pre-combination
    k_wcomb <<<NHEAD, 256, 0, stream>>>(W2, W3, Tm);
    k_wcombT<<<NHEAD, 256, 0, stream>>>(W1, Tm, Mt);
    k_cvec  <<<1, 128, 0, stream>>>(b1, b2, Tm, W3, cvec);

    const int TB = 256;
    // h -> bf16
    k_h2b<<<(int)(NB / 4 + TB - 1) / TB, TB, 0, stream>>>((const float4*)h, (ushort4*)hb,
                                                          (int)(NB / 4));
    // CSR build (no global atomics)
    k_p1count<<<NBLK1, 256, 0, stream>>>(gt_src, gt_dst, at_src, at_dst, blkcnt, E, N, Btot);
    int nsb = (n1 + 1023) / 1024;
    k_scan1<<<nsb, 256, 0, stream>>>(blkcnt, scn, part, n1);
    k_scan2<<<1, 256, 0, stream>>>(part, nsb);
    k_scan3<<<(n1 + TB - 1) / TB, TB, 0, stream>>>(scn, part, n1, 4 * E);
    k_p1scatter<<<NBLK1, 256, 0, stream>>>(gt_src, gt_dst, at_src, at_dst, scn,
                                           pairs, svals, E, N, Btot);
    k_p2<<<Btot, 256, 0, stream>>>(pairs, svals, scn, rowptr, csr, indeg, norms,
                                   E, N2, Btot);

    // pull passes (bf16 gathers): 8 nodes/block
    const int pgrid = (N + 7) / 8;
    for (int g = 0; g < 2; ++g) {
        const int* rp = rowptr + g * N;
        const float* ns = norms + g * N;
        float* Q = g ? Qat : Qgt;
        k_pull_avg<<<pgrid, 256, 0, stream>>>((const ushort4*)hb, rp, csr, ns,
                                              (ushort4*)bufAb, N, 0);
        k_pull_avg<<<pgrid, 256, 0, stream>>>((const ushort4*)bufAb, rp, csr, ns,
                                              (ushort4*)bufBb, N, 1);
        k_pull3<<<pgrid, 256, 0, stream>>>((const ushort4*)bufBb, rp, csr, ns,
                                           (float4*)Q, ssum + g * N, N);
    }

    // fused dense tail (32 rows/block)
    k_tail<<<(N + 31) / 32, 256, 0, stream>>>((const float4*)Qgt, (const float4*)Qat,
                                              ssum, indeg, Mt, cvec, b3, h, ln_g, ln_b,
                                              fW1, fb1, fW2, fb2, (float*)d_out, N);
}

// Round 7
// 393.702 us; speedup vs baseline: 5.2931x; 1.1161x over previous
//
#include <hip/hip_runtime.h>

#define DD 128
#define NHEAD 8
#define DH 16
#define EPS 1e-5f
#define BSH 9                 // bucket width 512 nodes
#define BWIDTH 512
#define NBLK1 256             // pass-1 blocks
#define QPAD 36               // padded row length for transposed LDS tiles

// ---------- bf16 helpers (OCP bf16 = f32 upper half, RNE) ----------
__device__ inline float4 up4(ushort4 u) {
    return make_float4(__uint_as_float((unsigned)u.x << 16),
                       __uint_as_float((unsigned)u.y << 16),
                       __uint_as_float((unsigned)u.z << 16),
                       __uint_as_float((unsigned)u.w << 16));
}
__device__ inline unsigned short f2b(float f) {
    unsigned u = __float_as_uint(f);
    u += 0x7fffu + ((u >> 16) & 1);
    return (unsigned short)(u >> 16);
}

// ================= h -> bf16 copy =================
__global__ void k_h2b(const float4* __restrict__ h4, ushort4* __restrict__ hb, int n4) {
    int i = blockIdx.x * 256 + threadIdx.x;
    if (i < n4) {
        float4 v = h4[i];
        hb[i] = make_ushort4(f2b(v.x), f2b(v.y), f2b(v.z), f2b(v.w));
    }
}

// ================= pass 1a: per-block bucket histograms =================
__global__ __launch_bounds__(256) void k_p1count(
        const int* __restrict__ gs, const int* __restrict__ gd,
        const int* __restrict__ as_, const int* __restrict__ ad,
        int* __restrict__ blkcnt, int E, int N, int Btot) {
    __shared__ int cnts[512];
    for (int j = threadIdx.x; j < 2 * Btot; j += 256) cnts[j] = 0;
    __syncthreads();
    int E2 = 2 * E;
    for (int i = blockIdx.x * 256 + threadIdx.x; i < E2; i += NBLK1 * 256) {
        int g = (i >= E);
        int e = g ? i - E : i;
        int s = g ? as_[e] : gs[e];
        int d = g ? ad[e] : gd[e];
        int cd = d + g * N, cs = s + g * N;
        atomicAdd(&cnts[cd >> BSH], 1);
        atomicAdd(&cnts[Btot + (cs >> BSH)], 1);
    }
    __syncthreads();
    for (int j = threadIdx.x; j < 2 * Btot; j += 256)
        blkcnt[j * NBLK1 + blockIdx.x] = cnts[j];
}

// ================= 3-stage scan =================
__global__ void k_scan1(const int* __restrict__ cnt, int* __restrict__ outv,
                        int* __restrict__ part, int n) {
    __shared__ int wsums[4];
    int t = threadIdx.x;
    int base = blockIdx.x * 1024 + t * 4;
    int v0 = 0, v1 = 0, v2 = 0, v3 = 0;
    if (base + 3 < n) {
        int4 q = *(const int4*)(cnt + base);
        v0 = q.x; v1 = q.y; v2 = q.z; v3 = q.w;
    } else {
        if (base < n)     v0 = cnt[base];
        if (base + 1 < n) v1 = cnt[base + 1];
        if (base + 2 < n) v2 = cnt[base + 2];
        if (base + 3 < n) v3 = cnt[base + 3];
    }
    int s0 = v0, s1 = s0 + v1, s2 = s1 + v2, s3 = s2 + v3;
    int x = s3;
    int lane = t & 63, w = t >> 6;
    for (int o = 1; o < 64; o <<= 1) { int u = __shfl_up(x, o); if (lane >= o) x += u; }
    if (lane == 63) wsums[w] = x;
    __syncthreads();
    int wo = 0;
    for (int i = 0; i < w; ++i) wo += wsums[i];
    int excl = wo + x - s3;
    if (base < n)     outv[base]     = excl;
    if (base + 1 < n) outv[base + 1] = excl + s0;
    if (base + 2 < n) outv[base + 2] = excl + s1;
    if (base + 3 < n) outv[base + 3] = excl + s2;
    if (t == 255) part[blockIdx.x] = wo + x;
}

__global__ void k_scan2(int* __restrict__ part, int nb) {
    __shared__ int ws[4];
    int t = threadIdx.x;
    int v = (t < nb) ? part[t] : 0;
    int x = v;
    int lane = t & 63, w = t >> 6;
    for (int o = 1; o < 64; o <<= 1) { int u = __shfl_up(x, o); if (lane >= o) x += u; }
    if (lane == 63) ws[w] = x;
    __syncthreads();
    int wo = 0;
    for (int i = 0; i < w; ++i) wo += ws[i];
    if (t < nb) part[t] = wo + x - v;
}

__global__ void k_scan3(int* __restrict__ outv, const int* __restrict__ part, int n, int total) {
    int i = blockIdx.x * blockDim.x + threadIdx.x;
    if (i < n) outv[i] += part[i >> 10];
    if (i == 0) outv[n] = total;
}

// ================= pass 1b: scatter edges into bucket regions =================
__global__ __launch_bounds__(256) void k_p1scatter(
        const int* __restrict__ gs, const int* __restrict__ gd,
        const int* __restrict__ as_, const int* __restrict__ ad,
        const int* __restrict__ scn, int2* __restrict__ pairs, int* __restrict__ svals,
        int E, int N, int Btot) {
    __shared__ int cur[512];
    for (int j = threadIdx.x; j < 2 * Btot; j += 256)
        cur[j] = scn[j * NBLK1 + blockIdx.x];
    __syncthreads();
    int E2 = 2 * E;
    for (int i = blockIdx.x * 256 + threadIdx.x; i < E2; i += NBLK1 * 256) {
        int g = (i >= E);
        int e = g ? i - E : i;
        int s = g ? as_[e] : gs[e];
        int d = g ? ad[e] : gd[e];
        int cd = d + g * N, cs = s + g * N;
        int pd = atomicAdd(&cur[cd >> BSH], 1);
        pairs[pd] = make_int2(cd, s);
        int ps = atomicAdd(&cur[Btot + (cs >> BSH)], 1);
        svals[ps - E2] = cs;
    }
}

// ================= pass 2: per-bucket CSR + indeg + norms =================
__global__ __launch_bounds__(256) void k_p2(
        const int2* __restrict__ pairs, const int* __restrict__ svals,
        const int* __restrict__ scn, int* __restrict__ rowptr, int* __restrict__ csr,
        float* __restrict__ indeg, float* __restrict__ norms,
        int E, int N2, int Btot) {
    __shared__ int hist[BWIDTH];
    __shared__ int offs[BWIDTH];
    __shared__ int cur[BWIDTH];
    __shared__ int ws4[4];
    int b = blockIdx.x, t = threadIdx.x;
    int node0 = b << BSH;
    int W = N2 - node0; if (W > BWIDTH) W = BWIDTH;
    int Sd = scn[b * NBLK1], Ed = scn[(b + 1) * NBLK1];
    hist[t] = 0; hist[t + 256] = 0;
    __syncthreads();
    for (int i = Sd + t; i < Ed; i += 256) {
        int2 p = pairs[i];
        atomicAdd(&hist[p.x - node0], 1);
    }
    __syncthreads();
    int a0 = hist[2 * t], a1 = hist[2 * t + 1];
    int sum2 = a0 + a1;
    int lane = t & 63, w = t >> 6;
    int x = sum2;
    for (int o = 1; o < 64; o <<= 1) { int u = __shfl_up(x, o); if (lane >= o) x += u; }
    if (lane == 63) ws4[w] = x;
    __syncthreads();
    int wo = 0;
    for (int i = 0; i < w; ++i) wo += ws4[i];
    int excl2 = wo + x - sum2;
    offs[2 * t] = excl2; offs[2 * t + 1] = excl2 + a0;
    cur[t] = 0; cur[t + 256] = 0;
    __syncthreads();
    for (int j = t; j < W; j += 256) {
        rowptr[node0 + j] = Sd + offs[j];
        indeg[node0 + j] = (float)hist[j];
    }
    if (b == 0 && t == 0) rowptr[N2] = 2 * E;
    for (int i = Sd + t; i < Ed; i += 256) {
        int2 p = pairs[i];
        int l = p.x - node0;
        int pos = atomicAdd(&cur[l], 1);
        csr[Sd + offs[l] + pos] = p.y;
    }
    __syncthreads();
    hist[t] = 0; hist[t + 256] = 0;
    __syncthreads();
    int Ss = scn[(Btot + b) * NBLK1] - 2 * E;
    int Es = scn[(Btot + b + 1) * NBLK1] - 2 * E;
    for (int i = Ss + t; i < Es; i += 256)
        atomicAdd(&hist[svals[i] - node0], 1);
    __syncthreads();
    for (int j = t; j < W; j += 256) {
        int od = hist[j];
        norms[node0 + j] = od > 0 ? rsqrtf((float)od) : 0.f;
    }
}

// ================= pull: avg (SAGE) over bf16 rows, optional norm-scale on output ========
__global__ __launch_bounds__(256) void k_pull_avg(
        const ushort4* __restrict__ xb, const int* __restrict__ rowptr,
        const int* __restrict__ csr, const float* __restrict__ norm_s,
        ushort4* __restrict__ outb, int N, int doscale) {
    int node = blockIdx.x * 8 + (threadIdx.x >> 5);
    int lane = threadIdx.x & 31;
    if (node >= N) return;
    int beg = rowptr[node], end = rowptr[node + 1];
    float4 a = up4(xb[(size_t)node * 32 + lane]);          // self term
    int e = beg;
    while (e < end) {
        int nb = end - e; if (nb > 32) nb = 32;
        int idx = (lane < nb) ? csr[e + lane] : 0;
        #pragma unroll 4
        for (int d = 0; d < nb; ++d) {
            int s = __shfl(idx, d, 32);
            float4 v = up4(xb[(size_t)s * 32 + lane]);
            a.x += v.x; a.y += v.y; a.z += v.z; a.w += v.w;
        }
        e += nb;
    }
    float sc = 1.f / (float)(end - beg + 1);
    if (doscale) sc *= norm_s[node];
    outb[(size_t)node * 32 + lane] =
        make_ushort4(f2b(a.x * sc), f2b(a.y * sc), f2b(a.z * sc), f2b(a.w * sc));
}

// ================= pull: plain sum of pre-scaled bf16 rows -> f32 Q, + ssum =================
__global__ __launch_bounds__(256) void k_pull3(
        const ushort4* __restrict__ Pb, const int* __restrict__ rowptr,
        const int* __restrict__ csr, const float* __restrict__ norm_s,
        float4* __restrict__ Q, float* __restrict__ ssum, int N) {
    int node = blockIdx.x * 8 + (threadIdx.x >> 5);
    int lane = threadIdx.x & 31;
    if (node >= N) return;
    int beg = rowptr[node], end = rowptr[node + 1];
    float4 a = make_float4(0.f, 0.f, 0.f, 0.f);
    float ss = 0.f;
    int e = beg;
    while (e < end) {
        int nb = end - e; if (nb > 32) nb = 32;
        int idx = (lane < nb) ? csr[e + lane] : 0;
        #pragma unroll 4
        for (int d = 0; d < nb; ++d) {
            int s = __shfl(idx, d, 32);
            float4 v = up4(Pb[(size_t)s * 32 + lane]);
            a.x += v.x; a.y += v.y; a.z += v.z; a.w += v.w;
            ss += norm_s[s];
        }
        e += nb;
    }
    Q[(size_t)node * 32 + lane] = a;
    if (lane == 0) ssum[node] = ss;
}

// ================= weight pre-combination =================
__global__ void k_wcomb(const float* __restrict__ A, const float* __restrict__ B,
                        float* __restrict__ C) {          // C[i] = A[i](128x128) @ B[i](128x16)
    int i = blockIdx.x;
    const float* Ai = A + (size_t)i * DD * DD;
    const float* Bi = B + (size_t)i * DD * DH;
    float* Ci = C + (size_t)i * DD * DH;
    for (int o = threadIdx.x; o < DD * DH; o += blockDim.x) {
        int r = o >> 4, c = o & 15;
        float acc = 0.f;
        #pragma unroll 8
        for (int k = 0; k < DD; ++k) acc += Ai[r * DD + k] * Bi[k * DH + c];
        Ci[o] = acc;
    }
}

// transposed variant: Mt[k][head*16+c] = (A[i] @ B[i])[k][c]
__global__ void k_wcombT(const float* __restrict__ A, const float* __restrict__ B,
                         float* __restrict__ Mt) {
    int i = blockIdx.x;
    const float* Ai = A + (size_t)i * DD * DD;
    const float* Bi = B + (size_t)i * DD * DH;
    for (int o = threadIdx.x; o < DD * DH; o += blockDim.x) {
        int r = o >> 4, c = o & 15;
        float acc = 0.f;
        #pragma unroll 8
        for (int k = 0; k < DD; ++k) acc += Ai[r * DD + k] * Bi[k * DH + c];
        Mt[r * DD + i * DH + c] = acc;
    }
}

__global__ void k_cvec(const float* __restrict__ b1, const float* __restrict__ b2,
                       const float* __restrict__ T, const float* __restrict__ W3,
                       float* __restrict__ cvec) {
    int idx = blockIdx.x * blockDim.x + threadIdx.x;
    if (idx >= NHEAD * DH) return;
    int i = idx >> 4, c = idx & 15;
    float acc = 0.f;
    for (int k = 0; k < DD; ++k)
        acc += b1[i * DD + k] * T[(size_t)i * DD * DH + k * DH + c]
             + b2[i * DD + k] * W3[(size_t)i * DD * DH + k * DH + c];
    cvec[idx] = acc;
}

// ================= fused tail: 4x4 register-tile GEMMs, transposed LDS operands ==========
// 256 thr; 32 rows/block. Thread (tr=t>>5, tc=t&31) owns rows 4tr..+3, cols 4tc..+3.
// Inner loop per k: 1 broadcast b128 (A from qT/xT/f1T) + 1 contiguous b128 (B from ws)
// + 16 FMAs. LDS: qT[2][128][36] (36 KB; xT->qT[0], f1T->qT[1] after GEMM1) + ws 16 KB = 52 KB.
__global__ __launch_bounds__(256) void k_tail(
        const float4* __restrict__ Qgt4, const float4* __restrict__ Qat4,
        const float* __restrict__ ssum, const float* __restrict__ indeg,
        const float* __restrict__ Mt, const float* __restrict__ cvec,
        const float* __restrict__ b3, const float* __restrict__ h,
        const float* __restrict__ ln_g, const float* __restrict__ ln_b,
        const float* __restrict__ fW1, const float* __restrict__ Fb1,
        const float* __restrict__ fW2, const float* __restrict__ Fb2,
        float* __restrict__ out, int N) {
    __shared__ float qT[2][DD][QPAD];     // [graph][k][row], 36864 B
    __shared__ float ws[32][DD];          // 16384 B
    int t = threadIdx.x;
    int tc = t & 31, tr = t >> 5;
    int C0 = 4 * tc, R0 = 4 * tr;
    int row0 = blockIdx.x * 32;

    // ---- stage Q transposed: idx -> r = idx&31 (row), c = idx>>5 (float4 col) ----
    #pragma unroll
    for (int i = 0; i < 4; ++i) {
        int idx = t + 256 * i;
        int r = idx & 31, c = idx >> 5;
        int gr = row0 + r; if (gr >= N) gr = N - 1;
        float4 q0 = Qgt4[(size_t)gr * 32 + c];
        float4 q1 = Qat4[(size_t)gr * 32 + c];
        qT[0][4 * c + 0][r] = q0.x; qT[0][4 * c + 1][r] = q0.y;
        qT[0][4 * c + 2][r] = q0.z; qT[0][4 * c + 3][r] = q0.w;
        qT[1][4 * c + 0][r] = q1.x; qT[1][4 * c + 1][r] = q1.y;
        qT[1][4 * c + 2][r] = q1.z; qT[1][4 * c + 3][r] = q1.w;
    }
    int g = (C0 >> 5) & 1;      // graph of this thread's 4 columns

    // ---- GEMM1: xcat = Q_g @ M ----
    float acc[4][4] = {};
    for (int kt = 0; kt < 4; ++kt) {
        __syncthreads();
        const float4* wsrc = (const float4*)(Mt + kt * 32 * DD);
        float4* wdst = (float4*)&ws[0][0];
        #pragma unroll
        for (int i = 0; i < 4; ++i) wdst[t + 256 * i] = wsrc[t + 256 * i];
        __syncthreads();
        #pragma unroll 4
        for (int kk = 0; kk < 32; ++kk) {
            float4 av = *(const float4*)&qT[g][kt * 32 + kk][R0];
            float4 bv = *(const float4*)&ws[kk][C0];
            acc[0][0] += av.x * bv.x; acc[0][1] += av.x * bv.y;
            acc[0][2] += av.x * bv.z; acc[0][3] += av.x * bv.w;
            acc[1][0] += av.y * bv.x; acc[1][1] += av.y * bv.y;
            acc[1][2] += av.y * bv.z; acc[1][3] += av.y * bv.w;
            acc[2][0] += av.z * bv.x; acc[2][1] += av.z * bv.y;
            acc[2][2] += av.z * bv.z; acc[2][3] += av.z * bv.w;
            acc[3][0] += av.w * bv.x; acc[3][1] += av.w * bv.y;
            acc[3][2] += av.w * bv.z; acc[3][3] += av.w * bv.w;
        }
    }
    // ---- epilogue1: (acc + ss*c)*nd + b3, LN over row (32-lane shfl), + residual ----
    float4 cv  = *(const float4*)&cvec[C0];
    float4 b3v = *(const float4*)&b3[C0];
    float4 glv = *(const float4*)&ln_g[C0];
    float4 blv = *(const float4*)&ln_b[C0];
    float xr[4][4];
    #pragma unroll
    for (int i = 0; i < 4; ++i) {
        int row = row0 + R0 + i;
        int rc = row < N ? row : N - 1;
        float ss = ssum[g * N + rc];
        float id = indeg[g * N + rc];
        float nd = id > 0.f ? rsqrtf(id) : 0.f;
        float v0 = (acc[i][0] + ss * cv.x) * nd + b3v.x;
        float v1 = (acc[i][1] + ss * cv.y) * nd + b3v.y;
        float v2 = (acc[i][2] + ss * cv.z) * nd + b3v.z;
        float v3 = (acc[i][3] + ss * cv.w) * nd + b3v.w;
        float s = v0 + v1 + v2 + v3;
        float s2 = v0 * v0 + v1 * v1 + v2 * v2 + v3 * v3;
        for (int o = 16; o > 0; o >>= 1) { s += __shfl_xor(s, o); s2 += __shfl_xor(s2, o); }
        float mu = s * (1.f / DD);
        float var = s2 * (1.f / DD) - mu * mu;
        float rs = rsqrtf(var + EPS);
        float4 hv = *(const float4*)&h[(size_t)rc * DD + C0];
        xr[i][0] = hv.x + (v0 - mu) * rs * glv.x + blv.x;
        xr[i][1] = hv.y + (v1 - mu) * rs * glv.y + blv.y;
        xr[i][2] = hv.z + (v2 - mu) * rs * glv.z + blv.z;
        xr[i][3] = hv.w + (v3 - mu) * rs * glv.w + blv.w;
    }
    __syncthreads();                       // all qT reads done before overwrite
    #pragma unroll
    for (int j = 0; j < 4; ++j)            // xT = qT[0]
        *(float4*)&qT[0][C0 + j][R0] =
            make_float4(xr[0][j], xr[1][j], xr[2][j], xr[3][j]);

    // ---- GEMM2: f1 = relu(x @ fW1 + Fb1) ----
    float ac2[4][4] = {};
    for (int kt = 0; kt < 4; ++kt) {
        __syncthreads();
        const float4* wsrc = (const float4*)(fW1 + kt * 32 * DD);
        float4* wdst = (float4*)&ws[0][0];
        #pragma unroll
        for (int i = 0; i < 4; ++i) wdst[t + 256 * i] = wsrc[t + 256 * i];
        __syncthreads();
        #pragma unroll 4
        for (int kk = 0; kk < 32; ++kk) {
            float4 av = *(const float4*)&qT[0][kt * 32 + kk][R0];
            float4 bv = *(const float4*)&ws[kk][C0];
            ac2[0][0] += av.x * bv.x; ac2[0][1] += av.x * bv.y;
            ac2[0][2] += av.x * bv.z; ac2[0][3] += av.x * bv.w;
            ac2[1][0] += av.y * bv.x; ac2[1][1] += av.y * bv.y;
            ac2[1][2] += av.y * bv.z; ac2[1][3] += av.y * bv.w;
            ac2[2][0] += av.z * bv.x; ac2[2][1] += av.z * bv.y;
            ac2[2][2] += av.z * bv.z; ac2[2][3] += av.z * bv.w;
            ac2[3][0] += av.w * bv.x; ac2[3][1] += av.w * bv.y;
            ac2[3][2] += av.w * bv.z; ac2[3][3] += av.w * bv.w;
        }
    }
    float4 fbv = *(const float4*)&Fb1[C0];
    #pragma unroll
    for (int j = 0; j < 4; ++j) {          // f1T = qT[1]
        float bj = j == 0 ? fbv.x : j == 1 ? fbv.y : j == 2 ? fbv.z : fbv.w;
        float w0 = ac2[0][j] + bj, w1 = ac2[1][j] + bj;
        float w2 = ac2[2][j] + bj, w3 = ac2[3][j] + bj;
        *(float4*)&qT[1][C0 + j][R0] =
            make_float4(w0 > 0.f ? w0 : 0.f, w1 > 0.f ? w1 : 0.f,
                        w2 > 0.f ? w2 : 0.f, w3 > 0.f ? w3 : 0.f);
    }

    // ---- GEMM3: out = x + LN(f1 @ fW2 + Fb2) ----
    float ac3[4][4] = {};
    for (int kt = 0; kt < 4; ++kt) {
        __syncthreads();                   // orders f1T writes before reads (kt=0)
        const float4* wsrc = (const float4*)(fW2 + kt * 32 * DD);
        float4* wdst = (float4*)&ws[0][0];
        #pragma unroll
        for (int i = 0; i < 4; ++i) wdst[t + 256 * i] = wsrc[t + 256 * i];
        __syncthreads();
        #pragma unroll 4
        for (int kk = 0; kk < 32; ++kk) {
            float4 av = *(const float4*)&qT[1][kt * 32 + kk][R0];
            float4 bv = *(const float4*)&ws[kk][C0];
            ac3[0][0] += av.x * bv.x; ac3[0][1] += av.x * bv.y;
            ac3[0][2] += av.x * bv.z; ac3[0][3] += av.x * bv.w;
            ac3[1][0] += av.y * bv.x; ac3[1][1] += av.y * bv.y;
            ac3[1][2] += av.y * bv.z; ac3[1][3] += av.y * bv.w;
            ac3[2][0] += av.z * bv.x; ac3[2][1] += av.z * bv.y;
            ac3[2][2] += av.z * bv.z; ac3[2][3] += av.z * bv.w;
            ac3[3][0] += av.w * bv.x; ac3[3][1] += av.w * bv.y;
            ac3[3][2] += av.w * bv.z; ac3[3][3] += av.w * bv.w;
        }
    }
    float4 gbv = *(const float4*)&Fb2[C0];
    #pragma unroll
    for (int i = 0; i < 4; ++i) {
        int row = row0 + R0 + i;
        float v0 = ac3[i][0] + gbv.x;
        float v1 = ac3[i][1] + gbv.y;
        float v2 = ac3[i][2] + gbv.z;
        float v3 = ac3[i][3] + gbv.w;
        float s = v0 + v1 + v2 + v3;
        float s2 = v0 * v0 + v1 * v1 + v2 * v2 + v3 * v3;
        for (int o = 16; o > 0; o >>= 1) { s += __shfl_xor(s, o); s2 += __shfl_xor(s2, o); }
        float mu = s * (1.f / DD);
        float var = s2 * (1.f / DD) - mu * mu;
        float rs = rsqrtf(var + EPS);
        if (row < N) {
            *(float4*)&out[(size_t)row * DD + C0] =
                make_float4(xr[i][0] + (v0 - mu) * rs * glv.x + blv.x,
                            xr[i][1] + (v1 - mu) * rs * glv.y + blv.y,
                            xr[i][2] + (v2 - mu) * rs * glv.z + blv.z,
                            xr[i][3] + (v3 - mu) * rs * glv.w + blv.w);
        }
    }
}

extern "C" void kernel_launch(void* const* d_in, const int* in_sizes, int n_in,
                              void* d_out, int out_size, void* d_ws, size_t ws_size,
                              hipStream_t stream) {
    const float* h      = (const float*)d_in[0];
    const int*   gt_src = (const int*)d_in[1];
    const int*   gt_dst = (const int*)d_in[2];
    const int*   at_src = (const int*)d_in[3];
    const int*   at_dst = (const int*)d_in[4];
    const float* W1     = (const float*)d_in[5];
    const float* b1     = (const float*)d_in[6];
    const float* W2     = (const float*)d_in[7];
    const float* b2     = (const float*)d_in[8];
    const float* W3     = (const float*)d_in[9];
    const float* b3     = (const float*)d_in[10];
    const float* fW1    = (const float*)d_in[11];
    const float* fb1    = (const float*)d_in[12];
    const float* fW2    = (const float*)d_in[13];
    const float* fb2    = (const float*)d_in[14];
    const float* ln_g   = (const float*)d_in[15];
    const float* ln_b   = (const float*)d_in[16];

    const int E = in_sizes[1];
    const int N = in_sizes[0] / DD;
    const size_t NB = (size_t)N * DD;
    const int N2 = 2 * N;
    const int Btot = (N2 + BWIDTH - 1) >> BSH;
    const int n1 = 2 * Btot * NBLK1;

    // ---- workspace layout ----
    float* w = (float*)d_ws;
    float* Qgt = w;                              // NB f32 (25.6 MB)
    unsigned short* hb    = (unsigned short*)(Qgt + NB);   // NB bf16
    unsigned short* bufAb = hb + NB;                       // NB bf16
    unsigned short* bufBb = bufAb + NB;                    // NB bf16
    float* sm = (float*)(bufBb + NB);
    float* norms = sm;  sm += N2;
    float* indeg = sm;  sm += N2;
    float* ssum  = sm;  sm += N2;
    float* Tm    = sm;  sm += (size_t)NHEAD * DD * DH;
    float* Mt    = sm;  sm += DD * DD;
    float* cvec  = sm;  sm += NHEAD * DH + 32;
    int* ip = (int*)sm;
    int* rowptr = ip;  ip += ((N2 + 1 + 3) & ~3);
    int* csr    = ip;  ip += 2 * E;
    int* blkcnt = ip;  ip += ((n1 + 1 + 3) & ~3);
    int* scn    = ip;  ip += ((n1 + 1 + 3) & ~3);
    int* part   = ip;  ip += 256;
    // CSR-build scratch aliased over Qgt (written only later, in pass 3)
    int2* pairs = (int2*)Qgt;                    // 2E int2 = 9.6 MB
    int*  svals = (int*)(pairs + 2 * E);         // 2E int  = 4.8 MB
    float* Qat  = (float*)d_out;                 // reuse d_out; overwritten by k_tail

    // weight pre-combination
    k_wcomb <<<NHEAD, 256, 0, stream>>>(W2, W3, Tm);
    k_wcombT<<<NHEAD, 256, 0, stream>>>(W1, Tm, Mt);
    k_cvec  <<<1, 128, 0, stream>>>(b1, b2, Tm, W3, cvec);

    const int TB = 256;
    // h -> bf16
    k_h2b<<<(int)(NB / 4 + TB - 1) / TB, TB, 0, stream>>>((const float4*)h, (ushort4*)hb,
                                                          (int)(NB / 4));
    // CSR build (no global atomics)
    k_p1count<<<NBLK1, 256, 0, stream>>>(gt_src, gt_dst, at_src, at_dst, blkcnt, E, N, Btot);
    int nsb = (n1 + 1023) / 1024;
    k_scan1<<<nsb, 256, 0, stream>>>(blkcnt, scn, part, n1);
    k_scan2<<<1, 256, 0, stream>>>(part, nsb);
    k_scan3<<<(n1 + TB - 1) / TB, TB, 0, stream>>>(scn, part, n1, 4 * E);
    k_p1scatter<<<NBLK1, 256, 0, stream>>>(gt_src, gt_dst, at_src, at_dst, scn,
                                           pairs, svals, E, N, Btot);
    k_p2<<<Btot, 256, 0, stream>>>(pairs, svals, scn, rowptr, csr, indeg, norms,
                                   E, N2, Btot);

    // pull passes (bf16 gathers): 8 nodes/block
    const int pgrid = (N + 7) / 8;
    for (int g = 0; g < 2; ++g) {
        const int* rp = rowptr + g * N;
        const float* ns = norms + g * N;
        float* Q = g ? Qat : Qgt;
        k_pull_avg<<<pgrid, 256, 0, stream>>>((const ushort4*)hb, rp, csr, ns,
                                              (ushort4*)bufAb, N, 0);
        k_pull_avg<<<pgrid, 256, 0, stream>>>((const ushort4*)bufAb, rp, csr, ns,
                                              (ushort4*)bufBb, N, 1);
        k_pull3<<<pgrid, 256, 0, stream>>>((const ushort4*)bufBb, rp, csr, ns,
                                           (float4*)Q, ssum + g * N, N);
    }

    // fused dense tail (32 rows/block, 4x4 register tiles)
    k_tail<<<(N + 31) / 32, 256, 0, stream>>>((const float4*)Qgt, (const float4*)Qat,
                                              ssum, indeg, Mt, cvec, b3, h, ln_g, ln_b,
                                              fW1, fb1, fW2, fb2, (float*)d_out, N);
}